// Round 3
// baseline (696.858 us; speedup 1.0000x reference)
//
#include <hip/hip_runtime.h>
#include <hip/hip_bf16.h>

#define N_NODES 50000
#define N_EDGES 500000
constexpr int HID = 64;
constexpr int HC  = 256;   // HEADS*HID

typedef unsigned short u16;
typedef unsigned char u8;
typedef __attribute__((ext_vector_type(8))) __bf16 bf16x8;
typedef __attribute__((ext_vector_type(4))) float f32x4;
typedef __attribute__((ext_vector_type(2))) float f32x2;

__device__ __forceinline__ float b2f(u16 u) {
    union { unsigned int i; float f; } c; c.i = ((unsigned int)u) << 16; return c.f;
}
__device__ __forceinline__ u16 f2b(float f) {
    union { float f; unsigned int i; } c; c.f = f;
    unsigned int x = c.i;
    unsigned int lsb = (x >> 16) & 1u;
    x += 0x7fffu + lsb;
    return (u16)(x >> 16);
}
__device__ __forceinline__ float elu_f(float x) { return x > 0.f ? x : expm1f(x); }

// kv fp8 layout (scale 16, e4m3): group g (8B) = [k ch 4g..4g+3][v ch 4g..4g+3]
// lane l reads 8B at kv + node*512 + l*8.

// ---------------- init: zero cnt/cursor ----------------
__global__ __launch_bounds__(256) void init_kernel(int* __restrict__ cnt, int* __restrict__ cursor) {
    int i = blockIdx.x * 256 + threadIdx.x;
    if (i < N_NODES) { cnt[i] = 0; cursor[i] = 0; }
}

// ---------------- edge_index layout detect (int32 vs int64) ----------------
__global__ __launch_bounds__(256) void detect_kernel(const int* __restrict__ ei, int* __restrict__ flag) {
    __shared__ int s[4];
    int t = threadIdx.x;
    int nz = ei[2 * t + 1] != 0;
    unsigned long long m = __ballot(nz);
    if ((t & 63) == 0) s[t >> 6] = (m != 0ull) ? 1 : 0;
    __syncthreads();
    if (t == 0) flag[0] = s[0] | s[1] | s[2] | s[3];   // 1 => int32 layout
}

// ---------------- weight pre-conversion fp32 -> bf16 (once) ----------------
__global__ __launch_bounds__(256) void wcvt_kernel(const float* __restrict__ Wq, const float* __restrict__ Wk,
                                                   const float* __restrict__ Wv, const float* __restrict__ Wsk,
                                                   u16* __restrict__ w16) {
    int i = blockIdx.x * 256 + threadIdx.x;   // float4 index
    if (i >= 53248) return;
    const float* src; int off;
    if (i < 16384)      { src = Wq;  off = i; }
    else if (i < 32768) { src = Wk;  off = i - 16384; }
    else if (i < 49152) { src = Wv;  off = i - 32768; }
    else                { src = Wsk; off = i - 49152; }
    float4 v = ((const float4*)src)[off];
    ushort4 u; u.x = f2b(v.x); u.y = f2b(v.y); u.z = f2b(v.z); u.w = f2b(v.w);
    ((ushort4*)w16)[i] = u;
}

// ---------------- CSR build (counting sort by dst) ----------------
__global__ __launch_bounds__(256) void hist_kernel(const int* __restrict__ ei, const int* __restrict__ flag,
                                                   int* __restrict__ cnt) {
    int e = blockIdx.x * 256 + threadIdx.x;
    if (e < N_EDGES) {
        int d = flag[0] ? ei[N_EDGES + e] : ei[2 * N_EDGES + 2 * e];
        atomicAdd(&cnt[d], 1);
    }
}

__global__ __launch_bounds__(512) void scan1_kernel(const int* __restrict__ cnt,
                                                    int* __restrict__ row_start, int* __restrict__ bsum) {
    __shared__ int sc[512];
    int t = threadIdx.x;
    int i = blockIdx.x * 512 + t;
    int v = (i < N_NODES) ? cnt[i] : 0;
    sc[t] = v;
    __syncthreads();
    for (int off = 1; off < 512; off <<= 1) {
        int u = (t >= off) ? sc[t - off] : 0;
        __syncthreads();
        sc[t] += u;
        __syncthreads();
    }
    if (i < N_NODES) row_start[i] = sc[t] - v;
    if (t == 511) bsum[blockIdx.x] = sc[511];
}

__global__ __launch_bounds__(128) void scan2_kernel(int* __restrict__ bsum, int* __restrict__ row_start) {
    __shared__ int sc[128];
    const int NB = (N_NODES + 511) / 512;  // 98
    int t = threadIdx.x;
    int v = (t < NB) ? bsum[t] : 0;
    sc[t] = v;
    __syncthreads();
    for (int off = 1; off < 128; off <<= 1) {
        int u = (t >= off) ? sc[t - off] : 0;
        __syncthreads();
        sc[t] += u;
        __syncthreads();
    }
    if (t < NB) bsum[t] = sc[t] - v;
    if (t == 127) row_start[N_NODES] = sc[127];
}

__global__ __launch_bounds__(512) void scan3_kernel(int* __restrict__ row_start, const int* __restrict__ bsum) {
    int i = blockIdx.x * 512 + threadIdx.x;
    if (i < N_NODES) row_start[i] += bsum[blockIdx.x];
}

__global__ __launch_bounds__(256) void scatter_kernel(const int* __restrict__ ei, const int* __restrict__ flag,
                                const int* __restrict__ row_start, int* __restrict__ cursor,
                                int* __restrict__ csr_src) {
    int e = blockIdx.x * 256 + threadIdx.x;
    if (e < N_EDGES) {
        int isI32 = flag[0];
        int s = isI32 ? ei[e] : ei[2 * e];
        int d = isI32 ? ei[N_EDGES + e] : ei[2 * N_EDGES + 2 * e];
        int pos = row_start[d] + atomicAdd(&cursor[d], 1);
        csr_src[pos] = s;
    }
}

// ---------------- Encoder: 8->64 elu (VALU) -> 64->64 elu (MFMA) ----------------
__global__ __launch_bounds__(256) void encoder_kernel(const float* __restrict__ x,
                               const float* __restrict__ w1, const float* __restrict__ b1,
                               const float* __restrict__ w2, const float* __restrict__ b2,
                               float* __restrict__ h) {
    __shared__ float xs[64 * 9];
    __shared__ float w1s[64 * 9];
    __shared__ u16 t1s[64 * 72];
    __shared__ u16 w2s[64 * 72];
    __shared__ float b1s[64], b2s[64];
    int t = threadIdx.x;
    int m0 = blockIdx.x * 64;

    if (t < 128) {
        int row = t >> 1, c = (t & 1) * 4;
        float4 val = make_float4(0.f, 0.f, 0.f, 0.f);
        if (m0 + row < N_NODES) val = *(const float4*)(x + (size_t)(m0 + row) * 8 + c);
        *(float4*)&xs[row * 9 + c] = val;
    }
    if (t >= 128 && t < 256) {
        int p = t - 128;
        int row = p >> 1, c = (p & 1) * 4;
        float4 val = *(const float4*)(w1 + row * 8 + c);
        *(float4*)&w1s[row * 9 + c] = val;
    }
    #pragma unroll
    for (int r = 0; r < 4; ++r) {
        int p = t + r * 256; int row = p >> 4, kc = (p & 15) * 4;
        float4 val = *(const float4*)(w2 + row * 64 + kc);
        ushort4 u; u.x = f2b(val.x); u.y = f2b(val.y); u.z = f2b(val.z); u.w = f2b(val.w);
        *(ushort4*)&w2s[row * 72 + kc] = u;
    }
    if (t < 64) { b1s[t] = b1[t]; b2s[t] = b2[t]; }
    __syncthreads();

    {
        int j = t & 63, sub = t >> 6;
        #pragma unroll
        for (int g = 0; g < 16; ++g) {
            int node = g * 4 + sub;
            float acc = b1s[j];
            #pragma unroll
            for (int m = 0; m < 8; ++m) acc += xs[node * 9 + m] * w1s[j * 9 + m];
            t1s[node * 72 + j] = f2b(elu_f(acc));
        }
    }
    __syncthreads();

    int wave = t >> 6, lane = t & 63;
    int lrow = lane & 15, quad = lane >> 4;
    int m_off = wave * 16;
    bf16x8 a0 = *(const bf16x8*)&t1s[(m_off + lrow) * 72 + quad * 8];
    bf16x8 a1 = *(const bf16x8*)&t1s[(m_off + lrow) * 72 + 32 + quad * 8];
    #pragma unroll
    for (int nsub = 0; nsub < 4; ++nsub) {
        bf16x8 b0 = *(const bf16x8*)&w2s[(nsub * 16 + lrow) * 72 + quad * 8];
        bf16x8 b1v = *(const bf16x8*)&w2s[(nsub * 16 + lrow) * 72 + 32 + quad * 8];
        f32x4 acc = {0.f, 0.f, 0.f, 0.f};
        acc = __builtin_amdgcn_mfma_f32_16x16x32_bf16(a0, b0, acc, 0, 0, 0);
        acc = __builtin_amdgcn_mfma_f32_16x16x32_bf16(a1, b1v, acc, 0, 0, 0);
        int col = nsub * 16 + lrow;
        float bias = b2s[col];
        #pragma unroll
        for (int r = 0; r < 4; ++r) {
            int row = m0 + m_off + quad * 4 + r;
            if (row < N_NODES) h[(size_t)row * 64 + col] = elu_f(acc[r] + bias);
        }
    }
}

// ---------------- Projection v2: direct global weight/h fragment loads (no
// input LDS staging, ~half the barriers), LDS staging kept for coalesced
// OUTPUT flushes only. ----------------
__global__ __launch_bounds__(256) void proj_kernel(const float* __restrict__ h,
    const u16* __restrict__ wq16, const u16* __restrict__ wk16,
    const u16* __restrict__ wv16, const u16* __restrict__ wsk16,
    const float* __restrict__ bq, const float* __restrict__ bk,
    const float* __restrict__ bv, const float* __restrict__ bsk,
    int layer,
    u16* __restrict__ q, u8* __restrict__ kv, float* __restrict__ skip)
{
    __shared__ float pool[64 * 68];      // 17408 B: qst u16[64*72] / kvst u8[64*144] / skst f32[64*68]
    u16* qst  = (u16*)pool;
    u8*  kvst = (u8*)pool;
    float* skst = pool;

    int t = threadIdx.x;
    int m0 = blockIdx.x * 64;
    int wave = t >> 6, lane = t & 63;
    int lrow = lane & 15, quad = lane >> 4;
    int nl = wave * 16 + lrow;          // node local index owned by this lane
    int grow_l = m0 + nl;

    // h fragment (B operand) loaded directly from global, fp32 -> bf16 in-reg
    bf16x8 a0, a1;
    {
        float4 f0 = make_float4(0.f,0.f,0.f,0.f), f1 = f0, f2 = f0, f3 = f0;
        if (grow_l < N_NODES) {
            const float* hr = h + (size_t)grow_l * 64;
            f0 = *(const float4*)(hr + quad * 8);
            f1 = *(const float4*)(hr + quad * 8 + 4);
            f2 = *(const float4*)(hr + 32 + quad * 8);
            f3 = *(const float4*)(hr + 32 + quad * 8 + 4);
        }
        union { bf16x8 v; u16 s[8]; } ua, ub;
        ua.s[0]=f2b(f0.x); ua.s[1]=f2b(f0.y); ua.s[2]=f2b(f0.z); ua.s[3]=f2b(f0.w);
        ua.s[4]=f2b(f1.x); ua.s[5]=f2b(f1.y); ua.s[6]=f2b(f1.z); ua.s[7]=f2b(f1.w);
        ub.s[0]=f2b(f2.x); ub.s[1]=f2b(f2.y); ub.s[2]=f2b(f2.z); ub.s[3]=f2b(f2.w);
        ub.s[4]=f2b(f3.x); ub.s[5]=f2b(f3.y); ub.s[6]=f2b(f3.z); ub.s[7]=f2b(f3.w);
        a0 = ua.v; a1 = ub.v;
    }

    const u16* Wq16  = wq16  + (size_t)layer * HC * HID;
    const u16* Wk16  = wk16  + (size_t)layer * HC * HID;
    const u16* Wv16  = wv16  + (size_t)layer * HC * HID;
    const u16* Wsk16 = wsk16 + (size_t)layer * HID * HID;
    const float* bqL  = bq  + layer * HC;
    const float* bkL  = bk  + layer * HC;
    const float* bvL  = bv  + layer * HC;
    const float* bskL = bsk + layer * HID;

    // ---- Q tiles ----
    for (int ct = 0; ct < 4; ++ct) {
        int cbase = ct * 64;
        #pragma unroll
        for (int nsub = 0; nsub < 4; ++nsub) {
            const u16* wr = Wq16 + (size_t)(cbase + nsub * 16 + lrow) * 64 + quad * 8;
            bf16x8 w0 = *(const bf16x8*)wr;
            bf16x8 w1 = *(const bf16x8*)(wr + 32);
            f32x4 acc = {0.f, 0.f, 0.f, 0.f};
            acc = __builtin_amdgcn_mfma_f32_16x16x32_bf16(w0, a0, acc, 0, 0, 0);
            acc = __builtin_amdgcn_mfma_f32_16x16x32_bf16(w1, a1, acc, 0, 0, 0);
            float4 b4 = *(const float4*)(bqL + cbase + nsub * 16 + quad * 4);
            ushort4 o;
            o.x = f2b(acc[0] + b4.x); o.y = f2b(acc[1] + b4.y);
            o.z = f2b(acc[2] + b4.z); o.w = f2b(acc[3] + b4.w);
            *(ushort4*)&qst[nl * 72 + nsub * 16 + quad * 4] = o;
        }
        __syncthreads();
        #pragma unroll
        for (int it = 0; it < 2; ++it) {
            int p = t + it * 256; int row = p >> 3, ch = p & 7;
            int grow = m0 + row;
            if (grow < N_NODES)
                *(uint4*)(q + (size_t)grow * 256 + cbase + ch * 8) = *(const uint4*)&qst[row * 72 + ch * 8];
        }
        __syncthreads();
    }

    // ---- KV tiles (k pass then v pass into interleaved staging, one flush) ----
    for (int ct = 0; ct < 4; ++ct) {
        int cbase = ct * 64;
        #pragma unroll
        for (int nsub = 0; nsub < 4; ++nsub) {
            const u16* wr = Wk16 + (size_t)(cbase + nsub * 16 + lrow) * 64 + quad * 8;
            bf16x8 w0 = *(const bf16x8*)wr;
            bf16x8 w1 = *(const bf16x8*)(wr + 32);
            f32x4 acc = {0.f, 0.f, 0.f, 0.f};
            acc = __builtin_amdgcn_mfma_f32_16x16x32_bf16(w0, a0, acc, 0, 0, 0);
            acc = __builtin_amdgcn_mfma_f32_16x16x32_bf16(w1, a1, acc, 0, 0, 0);
            float4 b4 = *(const float4*)(bkL + cbase + nsub * 16 + quad * 4);
            float f0 = (acc[0] + b4.x) * 16.f, f1 = (acc[1] + b4.y) * 16.f;
            float f2v = (acc[2] + b4.z) * 16.f, f3v = (acc[3] + b4.w) * 16.f;
            int pk = __builtin_amdgcn_cvt_pk_fp8_f32(f0, f1, 0, false);
            pk = __builtin_amdgcn_cvt_pk_fp8_f32(f2v, f3v, pk, true);
            int g = nsub * 4 + quad;
            *(unsigned int*)&kvst[nl * 144 + g * 8] = (unsigned int)pk;
        }
        #pragma unroll
        for (int nsub = 0; nsub < 4; ++nsub) {
            const u16* wr = Wv16 + (size_t)(cbase + nsub * 16 + lrow) * 64 + quad * 8;
            bf16x8 w0 = *(const bf16x8*)wr;
            bf16x8 w1 = *(const bf16x8*)(wr + 32);
            f32x4 acc = {0.f, 0.f, 0.f, 0.f};
            acc = __builtin_amdgcn_mfma_f32_16x16x32_bf16(w0, a0, acc, 0, 0, 0);
            acc = __builtin_amdgcn_mfma_f32_16x16x32_bf16(w1, a1, acc, 0, 0, 0);
            float4 b4 = *(const float4*)(bvL + cbase + nsub * 16 + quad * 4);
            float f0 = (acc[0] + b4.x) * 16.f, f1 = (acc[1] + b4.y) * 16.f;
            float f2v = (acc[2] + b4.z) * 16.f, f3v = (acc[3] + b4.w) * 16.f;
            int pk = __builtin_amdgcn_cvt_pk_fp8_f32(f0, f1, 0, false);
            pk = __builtin_amdgcn_cvt_pk_fp8_f32(f2v, f3v, pk, true);
            int g = nsub * 4 + quad;
            *(unsigned int*)&kvst[nl * 144 + g * 8 + 4] = (unsigned int)pk;
        }
        __syncthreads();
        #pragma unroll
        for (int it = 0; it < 2; ++it) {
            int p = t + it * 256; int row = p >> 3, ch = p & 7;
            int grow = m0 + row;
            if (grow < N_NODES)
                *(uint4*)(kv + (size_t)grow * 512 + cbase * 2 + ch * 16) = *(const uint4*)&kvst[row * 144 + ch * 16];
        }
        __syncthreads();
    }

    // ---- skip tile (fp32) ----
    {
        #pragma unroll
        for (int nsub = 0; nsub < 4; ++nsub) {
            const u16* wr = Wsk16 + (size_t)(nsub * 16 + lrow) * 64 + quad * 8;
            bf16x8 w0 = *(const bf16x8*)wr;
            bf16x8 w1 = *(const bf16x8*)(wr + 32);
            f32x4 acc = {0.f, 0.f, 0.f, 0.f};
            acc = __builtin_amdgcn_mfma_f32_16x16x32_bf16(w0, a0, acc, 0, 0, 0);
            acc = __builtin_amdgcn_mfma_f32_16x16x32_bf16(w1, a1, acc, 0, 0, 0);
            float4 b4 = *(const float4*)(bskL + nsub * 16 + quad * 4);
            float4 o;
            o.x = acc[0] + b4.x; o.y = acc[1] + b4.y;
            o.z = acc[2] + b4.z; o.w = acc[3] + b4.w;
            *(float4*)&skst[nl * 68 + nsub * 16 + quad * 4] = o;
        }
        __syncthreads();
        int row = t >> 2, c0 = (t & 3) * 16;
        int grow = m0 + row;
        if (grow < N_NODES) {
            #pragma unroll
            for (int j = 0; j < 4; ++j)
                *(float4*)(skip + (size_t)grow * 64 + c0 + j * 4) = *(const float4*)&skst[row * 68 + c0 + j * 4];
        }
    }
}

// ---------------- Attention v4: LDS-broadcast CSR + 8-deep gather pipeline
// (two quads of kv loads in flight before compute). Reduce (__shfl_xor) and
// exp (__expf) kept from the proven baseline. ----------------
#define KV_LOAD(cv, S) uint2 cv = *(const uint2*)(kvl + (size_t)(unsigned)(S) * 512)

#define ATTN_BODY(c0, c1, c2, c3, V1, V2, V3) do { \
    f32x2 k0a = __builtin_amdgcn_cvt_pk_f32_fp8(c0.x, false), k0b = __builtin_amdgcn_cvt_pk_f32_fp8(c0.x, true); \
    f32x2 k1a = __builtin_amdgcn_cvt_pk_f32_fp8(c1.x, false), k1b = __builtin_amdgcn_cvt_pk_f32_fp8(c1.x, true); \
    f32x2 k2a = __builtin_amdgcn_cvt_pk_f32_fp8(c2.x, false), k2b = __builtin_amdgcn_cvt_pk_f32_fp8(c2.x, true); \
    f32x2 k3a = __builtin_amdgcn_cvt_pk_f32_fp8(c3.x, false), k3b = __builtin_amdgcn_cvt_pk_f32_fp8(c3.x, true); \
    f32x2 pd0 = qlo * k0a + qhi * k0b; \
    f32x2 pd1 = qlo * k1a + qhi * k1b; \
    f32x2 pd2 = qlo * k2a + qhi * k2b; \
    f32x2 pd3 = qlo * k3a + qhi * k3b; \
    float p0 = pd0.x + pd0.y, p1 = pd1.x + pd1.y, p2 = pd2.x + pd2.y, p3 = pd3.x + pd3.y; \
    p0 += __shfl_xor(p0, 1); p1 += __shfl_xor(p1, 1); p2 += __shfl_xor(p2, 1); p3 += __shfl_xor(p3, 1); \
    p0 += __shfl_xor(p0, 2); p1 += __shfl_xor(p1, 2); p2 += __shfl_xor(p2, 2); p3 += __shfl_xor(p3, 2); \
    p0 += __shfl_xor(p0, 4); p1 += __shfl_xor(p1, 4); p2 += __shfl_xor(p2, 4); p3 += __shfl_xor(p3, 4); \
    p0 += __shfl_xor(p0, 8); p1 += __shfl_xor(p1, 8); p2 += __shfl_xor(p2, 8); p3 += __shfl_xor(p3, 8); \
    float w0 = __expf(p0 * SC); \
    float w1 = (V1) ? __expf(p1 * SC) : 0.f; \
    float w2 = (V2) ? __expf(p2 * SC) : 0.f; \
    float w3 = (V3) ? __expf(p3 * SC) : 0.f; \
    l += (w0 + w1) + (w2 + w3); \
    f32x2 v0a = __builtin_amdgcn_cvt_pk_f32_fp8(c0.y, false), v0b = __builtin_amdgcn_cvt_pk_f32_fp8(c0.y, true); \
    f32x2 v1a = __builtin_amdgcn_cvt_pk_f32_fp8(c1.y, false), v1b = __builtin_amdgcn_cvt_pk_f32_fp8(c1.y, true); \
    f32x2 v2a = __builtin_amdgcn_cvt_pk_f32_fp8(c2.y, false), v2b = __builtin_amdgcn_cvt_pk_f32_fp8(c2.y, true); \
    f32x2 v3a = __builtin_amdgcn_cvt_pk_f32_fp8(c3.y, false), v3b = __builtin_amdgcn_cvt_pk_f32_fp8(c3.y, true); \
    accA += v0a * w0; accA += v1a * w1; accA += v2a * w2; accA += v3a * w3; \
    accB += v0b * w0; accB += v1b * w1; accB += v2b * w2; accB += v3b * w3; \
} while (0)

__global__ __launch_bounds__(256) void attn_kernel(
    const u16* __restrict__ q, const u8* __restrict__ kv,
    const float* __restrict__ skip,
    const int* __restrict__ row_start, const int* __restrict__ csr_src,
    float* __restrict__ hout)
{
    __shared__ int s_lds[4][64];     // per-wave private row: no barrier needed
    int wave = threadIdx.x >> 6;
    int lane = threadIdx.x & 63;
    int n = blockIdx.x * 4 + wave;
    if (n >= N_NODES) return;
    ushort4 q4 = ((const ushort4*)(q + (size_t)n * 256))[lane];
    f32x2 qlo = { b2f(q4.x), b2f(q4.y) };
    f32x2 qhi = { b2f(q4.z), b2f(q4.w) };
    const u8* kvl = kv + lane * 8;
    const float SC = 0.0078125f;   // 1/(8*16)
    float l = 0.f;
    f32x2 accA = {0.f, 0.f};
    f32x2 accB = {0.f, 0.f};
    int e0 = row_start[n];
    int deg = row_start[n + 1] - e0;

    for (int base = 0; base < deg; base += 64) {
        int rem = deg - base;
        int m = rem < 64 ? rem : 64;
        int li = lane < m ? lane : m - 1;           // clamp: stay inside this row's edges
        s_lds[wave][lane] = csr_src[e0 + base + li]; // one coalesced load per 64 edges
        int i = 0;
        for (; i + 8 <= m; i += 8) {                // 8 gathers in flight per iter
            int4 sa = *(const int4*)&s_lds[wave][i];
            int4 sb = *(const int4*)&s_lds[wave][i + 4];
            KV_LOAD(c0, sa.x); KV_LOAD(c1, sa.y); KV_LOAD(c2, sa.z); KV_LOAD(c3, sa.w);
            KV_LOAD(d0, sb.x); KV_LOAD(d1, sb.y); KV_LOAD(d2, sb.z); KV_LOAD(d3, sb.w);
            ATTN_BODY(c0, c1, c2, c3, 1, 1, 1);
            ATTN_BODY(d0, d1, d2, d3, 1, 1, 1);
        }
        if (i + 4 <= m) {
            int4 sq = *(const int4*)&s_lds[wave][i];
            KV_LOAD(c0, sq.x); KV_LOAD(c1, sq.y); KV_LOAD(c2, sq.z); KV_LOAD(c3, sq.w);
            ATTN_BODY(c0, c1, c2, c3, 1, 1, 1);
            i += 4;
        }
        if (i < m) {                                  // tail: 1..3 edges, masked quad
            int4 sq = *(const int4*)&s_lds[wave][i];  // i%4==0, i<=60: aligned, in-bounds
            int rem2 = m - i;
            int sB = rem2 > 1 ? sq.y : sq.x;
            int sC = rem2 > 2 ? sq.z : sq.x;
            KV_LOAD(c0, sq.x); KV_LOAD(c1, sB); KV_LOAD(c2, sC); KV_LOAD(c3, sq.x);
            ATTN_BODY(c0, c1, c2, c3, rem2 > 1, rem2 > 2, 0);
        }
    }

    float inv = l > 0.f ? 1.f / l : 0.f;
    float a0 = accA.x * inv, a1 = accA.y * inv;
    float a2 = accB.x * inv, a3 = accB.y * inv;
    a0 += __shfl_xor(a0, 16); a0 += __shfl_xor(a0, 32);
    a1 += __shfl_xor(a1, 16); a1 += __shfl_xor(a1, 32);
    a2 += __shfl_xor(a2, 16); a2 += __shfl_xor(a2, 32);
    a3 += __shfl_xor(a3, 16); a3 += __shfl_xor(a3, 32);
    if ((lane >> 4) == 0) {
        const float OS = 0.015625f;  // 0.25 (head mean) * 1/16 (v scale)
        float4 sk = ((const float4*)(skip + (size_t)n * 64))[lane];
        float4 o;
        o.x = elu_f(OS * a0 + sk.x);
        o.y = elu_f(OS * a1 + sk.y);
        o.z = elu_f(OS * a2 + sk.z);
        o.w = elu_f(OS * a3 + sk.w);
        ((float4*)(hout + (size_t)n * 64))[lane] = o;
    }
}

// ---------------- Output MLP: 64->64 elu (MFMA) ->32 elu (MFMA) ->8 (VALU) ----------------
__global__ __launch_bounds__(256) void mlp_kernel(const float* __restrict__ h,
    const float* __restrict__ w1, const float* __restrict__ b1,
    const float* __restrict__ w2, const float* __restrict__ b2,
    const float* __restrict__ w3, const float* __restrict__ b3,
    float* __restrict__ out)
{
    __shared__ u16 hs[64 * 72];
    __shared__ u16 w1s[64 * 72];
    __shared__ u16 t1s[64 * 72];
    __shared__ u16 w2s[32 * 72];
    __shared__ float t2s[64 * 33];
    __shared__ float w3s[8 * 33];
    __shared__ float b1s[64], b2s[32], b3s[8];
    int t = threadIdx.x;
    int m0 = blockIdx.x * 64;

    #pragma unroll
    for (int r = 0; r < 4; ++r) {
        int p = t + r * 256; int row = p >> 4, kc = (p & 15) * 4;
        float4 val = make_float4(0.f, 0.f, 0.f, 0.f);
        if (m0 + row < N_NODES) val = *(const float4*)(h + (size_t)(m0 + row) * 64 + kc);
        ushort4 u; u.x = f2b(val.x); u.y = f2b(val.y); u.z = f2b(val.z); u.w = f2b(val.w);
        *(ushort4*)&hs[row * 72 + kc] = u;
    }
    #pragma unroll
    for (int r = 0; r < 4; ++r) {
        int p = t + r * 256; int row = p >> 4, kc = (p & 15) * 4;
        float4 val = *(const float4*)(w1 + row * 64 + kc);
        ushort4 u; u.x = f2b(val.x); u.y = f2b(val.y); u.z = f2b(val.z); u.w = f2b(val.w);
        *(ushort4*)&w1s[row * 72 + kc] = u;
    }
    #pragma unroll
    for (int r = 0; r < 2; ++r) {
        int p = t + r * 256; int row = p >> 4, kc = (p & 15) * 4;
        float4 val = *(const float4*)(w2 + row * 64 + kc);
        ushort4 u; u.x = f2b(val.x); u.y = f2b(val.y); u.z = f2b(val.z); u.w = f2b(val.w);
        *(ushort4*)&w2s[row * 72 + kc] = u;
    }
    if (t < 8 * 32) { int r = t >> 5, c = t & 31; w3s[r * 33 + c] = w3[t]; }
    if (t < 64) b1s[t] = b1[t];
    if (t >= 64 && t < 96) b2s[t - 64] = b2[t - 64];
    if (t >= 96 && t < 104) b3s[t - 96] = b3[t - 96];
    __syncthreads();

    int wave = t >> 6, lane = t & 63;
    int lrow = lane & 15, quad = lane >> 4;
    int m_off = wave * 16;

    {
        bf16x8 a0 = *(const bf16x8*)&hs[(m_off + lrow) * 72 + quad * 8];
        bf16x8 a1 = *(const bf16x8*)&hs[(m_off + lrow) * 72 + 32 + quad * 8];
        #pragma unroll
        for (int nsub = 0; nsub < 4; ++nsub) {
            bf16x8 b0 = *(const bf16x8*)&w1s[(nsub * 16 + lrow) * 72 + quad * 8];
            bf16x8 b1v = *(const bf16x8*)&w1s[(nsub * 16 + lrow) * 72 + 32 + quad * 8];
            f32x4 acc = {0.f, 0.f, 0.f, 0.f};
            acc = __builtin_amdgcn_mfma_f32_16x16x32_bf16(a0, b0, acc, 0, 0, 0);
            acc = __builtin_amdgcn_mfma_f32_16x16x32_bf16(a1, b1v, acc, 0, 0, 0);
            int col = nsub * 16 + lrow;
            float bias = b1s[col];
            #pragma unroll
            for (int r = 0; r < 4; ++r) {
                int row = m_off + quad * 4 + r;
                t1s[row * 72 + col] = f2b(elu_f(acc[r] + bias));
            }
        }
    }
    __syncthreads();

    {
        bf16x8 a0 = *(const bf16x8*)&t1s[(m_off + lrow) * 72 + quad * 8];
        bf16x8 a1 = *(const bf16x8*)&t1s[(m_off + lrow) * 72 + 32 + quad * 8];
        #pragma unroll
        for (int nsub = 0; nsub < 2; ++nsub) {
            bf16x8 b0 = *(const bf16x8*)&w2s[(nsub * 16 + lrow) * 72 + quad * 8];
            bf16x8 b1v = *(const bf16x8*)&w2s[(nsub * 16 + lrow) * 72 + 32 + quad * 8];
            f32x4 acc = {0.f, 0.f, 0.f, 0.f};
            acc = __builtin_amdgcn_mfma_f32_16x16x32_bf16(a0, b0, acc, 0, 0, 0);
            acc = __builtin_amdgcn_mfma_f32_16x16x32_bf16(a1, b1v, acc, 0, 0, 0);
            int col = nsub * 16 + lrow;
            float bias = b2s[col];
            #pragma unroll
            for (int r = 0; r < 4; ++r) {
                int row = m_off + quad * 4 + r;
                t2s[row * 33 + col] = elu_f(acc[r] + bias);
            }
        }
    }
    __syncthreads();

    #pragma unroll
    for (int r = 0; r < 2; ++r) {
        int idx = t + r * 256;
        int node = idx >> 3, j = idx & 7;
        int row = m0 + node;
        if (row < N_NODES) {
            float acc = b3s[j];
            #pragma unroll
            for (int kk = 0; kk < 32; ++kk) acc += t2s[node * 33 + kk] * w3s[j * 33 + kk];
            out[(size_t)row * 8 + j] = acc;
        }
    }
}

extern "C" void kernel_launch(void* const* d_in, const int* in_sizes, int n_in,
                              void* d_out, int out_size, void* d_ws, size_t ws_size,
                              hipStream_t stream) {
    (void)in_sizes; (void)n_in; (void)out_size; (void)ws_size;
    const float* x   = (const float*)d_in[0];
    const int* ei    = (const int*)d_in[1];
    const float* ew1 = (const float*)d_in[2];
    const float* eb1 = (const float*)d_in[3];
    const float* ew2 = (const float*)d_in[4];
    const float* eb2 = (const float*)d_in[5];
    const float* Wq  = (const float*)d_in[6];
    const float* bq  = (const float*)d_in[7];
    const float* Wk  = (const float*)d_in[8];
    const float* bk  = (const float*)d_in[9];
    const float* Wv  = (const float*)d_in[10];
    const float* bv  = (const float*)d_in[11];
    const float* Wsk = (const float*)d_in[12];
    const float* bsk = (const float*)d_in[13];
    const float* ow1 = (const float*)d_in[14];
    const float* ob1 = (const float*)d_in[15];
    const float* ow2 = (const float*)d_in[16];
    const float* ob2 = (const float*)d_in[17];
    const float* ow3 = (const float*)d_in[18];
    const float* ob3 = (const float*)d_in[19];

    char* ws = (char*)d_ws;
    size_t off = 0;
    auto alloc = [&](size_t bytes) -> void* {
        void* p = ws + off;
        off += (bytes + 255) & ~(size_t)255;
        return p;
    };
    float* h0    = (float*)alloc((size_t)N_NODES * 64 * 4);
    float* h1    = (float*)alloc((size_t)N_NODES * 64 * 4);
    u16*   q     = (u16*)  alloc((size_t)N_NODES * 256 * 2);
    u8*    kv    = (u8*)   alloc((size_t)N_NODES * 512);
    float* skp   = (float*)alloc((size_t)N_NODES * 64 * 4);
    u16*   w16   = (u16*)  alloc((size_t)212992 * 2);
    int*   cnt   = (int*)  alloc((size_t)N_NODES * 4);
    int*   cursor= (int*)  alloc((size_t)N_NODES * 4);
    int*   rowst = (int*)  alloc((size_t)(N_NODES + 1) * 4);
    int*   csr   = (int*)  alloc((size_t)N_EDGES * 4);
    int*   bsum  = (int*)  alloc(512);
    int*   flag  = (int*)  alloc(256);

    u16* wq16  = w16;
    u16* wk16  = w16 + 65536;
    u16* wv16  = w16 + 131072;
    u16* wsk16 = w16 + 196608;

    const int NB = (N_NODES + 511) / 512;   // 98 scan blocks

    init_kernel<<<(N_NODES + 255) / 256, 256, 0, stream>>>(cnt, cursor);
    detect_kernel<<<1, 256, 0, stream>>>(ei, flag);
    wcvt_kernel<<<208, 256, 0, stream>>>(Wq, Wk, Wv, Wsk, w16);
    hist_kernel<<<(N_EDGES + 255) / 256, 256, 0, stream>>>(ei, flag, cnt);
    scan1_kernel<<<NB, 512, 0, stream>>>(cnt, rowst, bsum);
    scan2_kernel<<<1, 128, 0, stream>>>(bsum, rowst);
    scan3_kernel<<<NB, 512, 0, stream>>>(rowst, bsum);
    scatter_kernel<<<(N_EDGES + 255) / 256, 256, 0, stream>>>(ei, flag, rowst, cursor, csr);

    encoder_kernel<<<(N_NODES + 63) / 64, 256, 0, stream>>>(x, ew1, eb1, ew2, eb2, h0);

    float* hin = h0;
    float* hout = h1;
    for (int l = 0; l < 4; ++l) {
        proj_kernel<<<(N_NODES + 63) / 64, 256, 0, stream>>>(hin, wq16, wk16, wv16, wsk16,
                                                             bq, bk, bv, bsk, l, q, kv, skp);
        attn_kernel<<<(N_NODES + 3) / 4, 256, 0, stream>>>(q, kv, skp, rowst, csr, hout);
        float* tmp = hin; hin = hout; hout = tmp;
    }

    mlp_kernel<<<(N_NODES + 63) / 64, 256, 0, stream>>>(hin, ow1, ob1, ow2, ob2, ow3, ob3, (float*)d_out);
}

// Round 4
// 523.539 us; speedup vs baseline: 1.3311x; 1.3311x over previous
//
#include <hip/hip_runtime.h>
#include <hip/hip_bf16.h>

#define N_NODES 50000
#define N_EDGES 500000
constexpr int HID = 64;
constexpr int HC  = 256;   // HEADS*HID

typedef unsigned short u16;
typedef unsigned char u8;
typedef __attribute__((ext_vector_type(8))) __bf16 bf16x8;
typedef __attribute__((ext_vector_type(4))) float f32x4;
typedef __attribute__((ext_vector_type(2))) float f32x2;

__device__ __forceinline__ float b2f(u16 u) {
    union { unsigned int i; float f; } c; c.i = ((unsigned int)u) << 16; return c.f;
}
__device__ __forceinline__ u16 f2b(float f) {
    union { float f; unsigned int i; } c; c.f = f;
    unsigned int x = c.i;
    unsigned int lsb = (x >> 16) & 1u;
    x += 0x7fffu + lsb;
    return (u16)(x >> 16);
}
__device__ __forceinline__ float elu_f(float x) { return x > 0.f ? x : expm1f(x); }

// h is stored bf16 (u16) everywhere: every consumer converts to bf16 before
// use anyway, so storing bf16 at the producer is bit-identical downstream.
// kv fp8 layout (scale 16, e4m3): group g (8B) = [k ch 4g..4g+3][v ch 4g..4g+3]

// ---------------- edge_index layout detect (int32 vs int64) ----------------
__global__ __launch_bounds__(256) void detect_kernel(const int* __restrict__ ei, int* __restrict__ flag) {
    __shared__ int s[4];
    int t = threadIdx.x;
    int nz = ei[2 * t + 1] != 0;
    unsigned long long m = __ballot(nz);
    if ((t & 63) == 0) s[t >> 6] = (m != 0ull) ? 1 : 0;
    __syncthreads();
    if (t == 0) flag[0] = s[0] | s[1] | s[2] | s[3];   // 1 => int32 layout
}

// ---------------- weight pre-conversion fp32 -> bf16 (once) ----------------
__global__ __launch_bounds__(256) void wcvt_kernel(const float* __restrict__ Wq, const float* __restrict__ Wk,
                                                   const float* __restrict__ Wv, const float* __restrict__ Wsk,
                                                   u16* __restrict__ w16) {
    int i = blockIdx.x * 256 + threadIdx.x;   // float4 index
    if (i >= 53248) return;
    const float* src; int off;
    if (i < 16384)      { src = Wq;  off = i; }
    else if (i < 32768) { src = Wk;  off = i - 16384; }
    else if (i < 49152) { src = Wv;  off = i - 32768; }
    else                { src = Wsk; off = i - 49152; }
    float4 v = ((const float4*)src)[off];
    ushort4 u; u.x = f2b(v.x); u.y = f2b(v.y); u.z = f2b(v.z); u.w = f2b(v.w);
    ((ushort4*)w16)[i] = u;
}

// ---------------- CSR build (counting sort by dst) ----------------
__global__ __launch_bounds__(256) void hist_kernel(const int* __restrict__ ei, const int* __restrict__ flag,
                                                   int* __restrict__ cnt) {
    int e = blockIdx.x * 256 + threadIdx.x;
    if (e < N_EDGES) {
        int d = flag[0] ? ei[N_EDGES + e] : ei[2 * N_EDGES + 2 * e];
        atomicAdd(&cnt[d], 1);
    }
}

__global__ __launch_bounds__(512) void scan1_kernel(const int* __restrict__ cnt,
                                                    int* __restrict__ row_start, int* __restrict__ bsum) {
    __shared__ int sc[512];
    int t = threadIdx.x;
    int i = blockIdx.x * 512 + t;
    int v = (i < N_NODES) ? cnt[i] : 0;
    sc[t] = v;
    __syncthreads();
    for (int off = 1; off < 512; off <<= 1) {
        int u = (t >= off) ? sc[t - off] : 0;
        __syncthreads();
        sc[t] += u;
        __syncthreads();
    }
    if (i < N_NODES) row_start[i] = sc[t] - v;
    if (t == 511) bsum[blockIdx.x] = sc[511];
}

__global__ __launch_bounds__(128) void scan2_kernel(int* __restrict__ bsum, int* __restrict__ row_start) {
    __shared__ int sc[128];
    const int NB = (N_NODES + 511) / 512;  // 98
    int t = threadIdx.x;
    int v = (t < NB) ? bsum[t] : 0;
    sc[t] = v;
    __syncthreads();
    for (int off = 1; off < 128; off <<= 1) {
        int u = (t >= off) ? sc[t - off] : 0;
        __syncthreads();
        sc[t] += u;
        __syncthreads();
    }
    if (t < NB) bsum[t] = sc[t] - v;
    if (t == 127) row_start[N_NODES] = sc[127];
}

__global__ __launch_bounds__(512) void scan3_kernel(int* __restrict__ row_start, const int* __restrict__ bsum) {
    int i = blockIdx.x * 512 + threadIdx.x;
    if (i < N_NODES) row_start[i] += bsum[blockIdx.x];
}

__global__ __launch_bounds__(256) void scatter_kernel(const int* __restrict__ ei, const int* __restrict__ flag,
                                const int* __restrict__ row_start, int* __restrict__ cursor,
                                int* __restrict__ csr_src) {
    int e = blockIdx.x * 256 + threadIdx.x;
    if (e < N_EDGES) {
        int isI32 = flag[0];
        int s = isI32 ? ei[e] : ei[2 * e];
        int d = isI32 ? ei[N_EDGES + e] : ei[2 * N_EDGES + 2 * e];
        int pos = row_start[d] + atomicAdd(&cursor[d], 1);
        csr_src[pos] = s;
    }
}

// ---------------- Encoder: 8->64 elu (VALU) -> 64->64 elu (MFMA), bf16 out ----------------
__global__ __launch_bounds__(256) void encoder_kernel(const float* __restrict__ x,
                               const float* __restrict__ w1, const float* __restrict__ b1,
                               const float* __restrict__ w2, const float* __restrict__ b2,
                               u16* __restrict__ h) {
    __shared__ float xs[64 * 9];
    __shared__ float w1s[64 * 9];
    __shared__ u16 t1s[64 * 72];
    __shared__ u16 w2s[64 * 72];
    __shared__ float b1s[64], b2s[64];
    int t = threadIdx.x;
    int m0 = blockIdx.x * 64;

    if (t < 128) {
        int row = t >> 1, c = (t & 1) * 4;
        float4 val = make_float4(0.f, 0.f, 0.f, 0.f);
        if (m0 + row < N_NODES) val = *(const float4*)(x + (size_t)(m0 + row) * 8 + c);
        *(float4*)&xs[row * 9 + c] = val;
    }
    if (t >= 128 && t < 256) {
        int p = t - 128;
        int row = p >> 1, c = (p & 1) * 4;
        float4 val = *(const float4*)(w1 + row * 8 + c);
        *(float4*)&w1s[row * 9 + c] = val;
    }
    #pragma unroll
    for (int r = 0; r < 4; ++r) {
        int p = t + r * 256; int row = p >> 4, kc = (p & 15) * 4;
        float4 val = *(const float4*)(w2 + row * 64 + kc);
        ushort4 u; u.x = f2b(val.x); u.y = f2b(val.y); u.z = f2b(val.z); u.w = f2b(val.w);
        *(ushort4*)&w2s[row * 72 + kc] = u;
    }
    if (t < 64) { b1s[t] = b1[t]; b2s[t] = b2[t]; }
    __syncthreads();

    {
        int j = t & 63, sub = t >> 6;
        #pragma unroll
        for (int g = 0; g < 16; ++g) {
            int node = g * 4 + sub;
            float acc = b1s[j];
            #pragma unroll
            for (int m = 0; m < 8; ++m) acc += xs[node * 9 + m] * w1s[j * 9 + m];
            t1s[node * 72 + j] = f2b(elu_f(acc));
        }
    }
    __syncthreads();

    int wave = t >> 6, lane = t & 63;
    int lrow = lane & 15, quad = lane >> 4;
    int m_off = wave * 16;
    bf16x8 a0 = *(const bf16x8*)&t1s[(m_off + lrow) * 72 + quad * 8];
    bf16x8 a1 = *(const bf16x8*)&t1s[(m_off + lrow) * 72 + 32 + quad * 8];
    #pragma unroll
    for (int nsub = 0; nsub < 4; ++nsub) {
        bf16x8 b0 = *(const bf16x8*)&w2s[(nsub * 16 + lrow) * 72 + quad * 8];
        bf16x8 b1v = *(const bf16x8*)&w2s[(nsub * 16 + lrow) * 72 + 32 + quad * 8];
        f32x4 acc = {0.f, 0.f, 0.f, 0.f};
        acc = __builtin_amdgcn_mfma_f32_16x16x32_bf16(a0, b0, acc, 0, 0, 0);
        acc = __builtin_amdgcn_mfma_f32_16x16x32_bf16(a1, b1v, acc, 0, 0, 0);
        int col = nsub * 16 + lrow;
        float bias = b2s[col];
        #pragma unroll
        for (int r = 0; r < 4; ++r) {
            int row = m0 + m_off + quad * 4 + r;
            if (row < N_NODES) h[(size_t)row * 64 + col] = f2b(elu_f(acc[r] + bias));
        }
    }
}

// ---------------- Projection (round-1 staged structure, bf16 h input) ----------------
__global__ __launch_bounds__(256) void proj_kernel(const u16* __restrict__ h,
    const u16* __restrict__ wq16, const u16* __restrict__ wk16,
    const u16* __restrict__ wv16, const u16* __restrict__ wsk16,
    const float* __restrict__ bq, const float* __restrict__ bk,
    const float* __restrict__ bv, const float* __restrict__ bsk,
    int layer,
    u16* __restrict__ q, u8* __restrict__ kv, float* __restrict__ skip)
{
    __shared__ u16 as_tile[64 * 72];     // h tile bf16 (B operand: node frags)
    __shared__ u16 ws_tile[64 * 72];     // weight tile bf16 (A operand)
    __shared__ float pool[64 * 68];      // 17408 B: qst u16[64*72] / kvst u8[64*144] / skst f32[64*68]
    u16* qst  = (u16*)pool;
    u8*  kvst = (u8*)pool;
    float* skst = pool;

    int t = threadIdx.x;
    int m0 = blockIdx.x * 64;

    // stage A (h rows, already bf16): 8KB via 2 x uint4 per thread
    #pragma unroll
    for (int it = 0; it < 2; ++it) {
        int p = t + it * 256; int row = p >> 3, kc = (p & 7) * 8;
        uint4 val = make_uint4(0u, 0u, 0u, 0u);
        if (m0 + row < N_NODES) val = *(const uint4*)(h + (size_t)(m0 + row) * 64 + kc);
        *(uint4*)&as_tile[row * 72 + kc] = val;
    }
    __syncthreads();

    int wave = t >> 6, lane = t & 63;
    int lrow = lane & 15, quad = lane >> 4;
    // h fragment (B operand): lane&15 = node within this wave's 16-node block
    bf16x8 a0 = *(const bf16x8*)&as_tile[(wave * 16 + lrow) * 72 + quad * 8];
    bf16x8 a1 = *(const bf16x8*)&as_tile[(wave * 16 + lrow) * 72 + 32 + quad * 8];

    const u16* Wq16  = wq16  + (size_t)layer * HC * HID;
    const u16* Wk16  = wk16  + (size_t)layer * HC * HID;
    const u16* Wv16  = wv16  + (size_t)layer * HC * HID;
    const u16* Wsk16 = wsk16 + (size_t)layer * HID * HID;
    const float* bqL  = bq  + layer * HC;
    const float* bkL  = bk  + layer * HC;
    const float* bvL  = bv  + layer * HC;
    const float* bskL = bsk + layer * HID;

    int nl = wave * 16 + lrow;          // node local index owned by this lane

    // ---- Q tiles ----
    for (int ct = 0; ct < 4; ++ct) {
        int cbase = ct * 64;
        __syncthreads();   // previous flush done; ws_tile free
        #pragma unroll
        for (int it = 0; it < 2; ++it) {
            int p = t + it * 256; int row = p >> 3, kc = (p & 7) * 8;
            *(uint4*)&ws_tile[row * 72 + kc] = *(const uint4*)(Wq16 + (size_t)(cbase + row) * 64 + kc);
        }
        __syncthreads();
        #pragma unroll
        for (int nsub = 0; nsub < 4; ++nsub) {
            bf16x8 w0 = *(const bf16x8*)&ws_tile[(nsub * 16 + lrow) * 72 + quad * 8];
            bf16x8 w1 = *(const bf16x8*)&ws_tile[(nsub * 16 + lrow) * 72 + 32 + quad * 8];
            f32x4 acc = {0.f, 0.f, 0.f, 0.f};
            acc = __builtin_amdgcn_mfma_f32_16x16x32_bf16(w0, a0, acc, 0, 0, 0);
            acc = __builtin_amdgcn_mfma_f32_16x16x32_bf16(w1, a1, acc, 0, 0, 0);
            float4 b4 = *(const float4*)(bqL + cbase + nsub * 16 + quad * 4);
            ushort4 o;
            o.x = f2b(acc[0] + b4.x); o.y = f2b(acc[1] + b4.y);
            o.z = f2b(acc[2] + b4.z); o.w = f2b(acc[3] + b4.w);
            *(ushort4*)&qst[nl * 72 + nsub * 16 + quad * 4] = o;
        }
        __syncthreads();
        #pragma unroll
        for (int it = 0; it < 2; ++it) {
            int p = t + it * 256; int row = p >> 3, ch = p & 7;
            int grow = m0 + row;
            if (grow < N_NODES)
                *(uint4*)(q + (size_t)grow * 256 + cbase + ch * 8) = *(const uint4*)&qst[row * 72 + ch * 8];
        }
    }

    // ---- KV tiles (k pass then v pass into interleaved staging, one flush) ----
    for (int ct = 0; ct < 4; ++ct) {
        int cbase = ct * 64;
        __syncthreads();
        #pragma unroll
        for (int it = 0; it < 2; ++it) {
            int p = t + it * 256; int row = p >> 3, kc = (p & 7) * 8;
            *(uint4*)&ws_tile[row * 72 + kc] = *(const uint4*)(Wk16 + (size_t)(cbase + row) * 64 + kc);
        }
        __syncthreads();
        #pragma unroll
        for (int nsub = 0; nsub < 4; ++nsub) {
            bf16x8 w0 = *(const bf16x8*)&ws_tile[(nsub * 16 + lrow) * 72 + quad * 8];
            bf16x8 w1 = *(const bf16x8*)&ws_tile[(nsub * 16 + lrow) * 72 + 32 + quad * 8];
            f32x4 acc = {0.f, 0.f, 0.f, 0.f};
            acc = __builtin_amdgcn_mfma_f32_16x16x32_bf16(w0, a0, acc, 0, 0, 0);
            acc = __builtin_amdgcn_mfma_f32_16x16x32_bf16(w1, a1, acc, 0, 0, 0);
            float4 b4 = *(const float4*)(bkL + cbase + nsub * 16 + quad * 4);
            float f0 = (acc[0] + b4.x) * 16.f, f1 = (acc[1] + b4.y) * 16.f;
            float f2v = (acc[2] + b4.z) * 16.f, f3v = (acc[3] + b4.w) * 16.f;
            int pk = __builtin_amdgcn_cvt_pk_fp8_f32(f0, f1, 0, false);
            pk = __builtin_amdgcn_cvt_pk_fp8_f32(f2v, f3v, pk, true);
            int g = nsub * 4 + quad;
            *(unsigned int*)&kvst[nl * 144 + g * 8] = (unsigned int)pk;
        }
        __syncthreads();
        #pragma unroll
        for (int it = 0; it < 2; ++it) {
            int p = t + it * 256; int row = p >> 3, kc = (p & 7) * 8;
            *(uint4*)&ws_tile[row * 72 + kc] = *(const uint4*)(Wv16 + (size_t)(cbase + row) * 64 + kc);
        }
        __syncthreads();
        #pragma unroll
        for (int nsub = 0; nsub < 4; ++nsub) {
            bf16x8 w0 = *(const bf16x8*)&ws_tile[(nsub * 16 + lrow) * 72 + quad * 8];
            bf16x8 w1 = *(const bf16x8*)&ws_tile[(nsub * 16 + lrow) * 72 + 32 + quad * 8];
            f32x4 acc = {0.f, 0.f, 0.f, 0.f};
            acc = __builtin_amdgcn_mfma_f32_16x16x32_bf16(w0, a0, acc, 0, 0, 0);
            acc = __builtin_amdgcn_mfma_f32_16x16x32_bf16(w1, a1, acc, 0, 0, 0);
            float4 b4 = *(const float4*)(bvL + cbase + nsub * 16 + quad * 4);
            float f0 = (acc[0] + b4.x) * 16.f, f1 = (acc[1] + b4.y) * 16.f;
            float f2v = (acc[2] + b4.z) * 16.f, f3v = (acc[3] + b4.w) * 16.f;
            int pk = __builtin_amdgcn_cvt_pk_fp8_f32(f0, f1, 0, false);
            pk = __builtin_amdgcn_cvt_pk_fp8_f32(f2v, f3v, pk, true);
            int g = nsub * 4 + quad;
            *(unsigned int*)&kvst[nl * 144 + g * 8 + 4] = (unsigned int)pk;
        }
        __syncthreads();
        #pragma unroll
        for (int it = 0; it < 2; ++it) {
            int p = t + it * 256; int row = p >> 3, ch = p & 7;
            int grow = m0 + row;
            if (grow < N_NODES)
                *(uint4*)(kv + (size_t)grow * 512 + cbase * 2 + ch * 16) = *(const uint4*)&kvst[row * 144 + ch * 16];
        }
    }

    // ---- skip tile (fp32) ----
    {
        __syncthreads();
        #pragma unroll
        for (int it = 0; it < 2; ++it) {
            int p = t + it * 256; int row = p >> 3, kc = (p & 7) * 8;
            *(uint4*)&ws_tile[row * 72 + kc] = *(const uint4*)(Wsk16 + (size_t)row * 64 + kc);
        }
        __syncthreads();
        #pragma unroll
        for (int nsub = 0; nsub < 4; ++nsub) {
            bf16x8 w0 = *(const bf16x8*)&ws_tile[(nsub * 16 + lrow) * 72 + quad * 8];
            bf16x8 w1 = *(const bf16x8*)&ws_tile[(nsub * 16 + lrow) * 72 + 32 + quad * 8];
            f32x4 acc = {0.f, 0.f, 0.f, 0.f};
            acc = __builtin_amdgcn_mfma_f32_16x16x32_bf16(w0, a0, acc, 0, 0, 0);
            acc = __builtin_amdgcn_mfma_f32_16x16x32_bf16(w1, a1, acc, 0, 0, 0);
            float4 b4 = *(const float4*)(bskL + nsub * 16 + quad * 4);
            float4 o;
            o.x = acc[0] + b4.x; o.y = acc[1] + b4.y;
            o.z = acc[2] + b4.z; o.w = acc[3] + b4.w;
            *(float4*)&skst[nl * 68 + nsub * 16 + quad * 4] = o;
        }
        __syncthreads();
        int row = t >> 2, c0 = (t & 3) * 16;
        int grow = m0 + row;
        if (grow < N_NODES) {
            #pragma unroll
            for (int j = 0; j < 4; ++j)
                *(float4*)(skip + (size_t)grow * 64 + c0 + j * 4) = *(const float4*)&skst[row * 68 + c0 + j * 4];
        }
    }
}

// ---------------- Attention v4: LDS-broadcast CSR + 8-deep gather pipeline,
// bf16 h output. ----------------
#define KV_LOAD(cv, S) uint2 cv = *(const uint2*)(kvl + (size_t)(unsigned)(S) * 512)

#define ATTN_BODY(c0, c1, c2, c3, V1, V2, V3) do { \
    f32x2 k0a = __builtin_amdgcn_cvt_pk_f32_fp8(c0.x, false), k0b = __builtin_amdgcn_cvt_pk_f32_fp8(c0.x, true); \
    f32x2 k1a = __builtin_amdgcn_cvt_pk_f32_fp8(c1.x, false), k1b = __builtin_amdgcn_cvt_pk_f32_fp8(c1.x, true); \
    f32x2 k2a = __builtin_amdgcn_cvt_pk_f32_fp8(c2.x, false), k2b = __builtin_amdgcn_cvt_pk_f32_fp8(c2.x, true); \
    f32x2 k3a = __builtin_amdgcn_cvt_pk_f32_fp8(c3.x, false), k3b = __builtin_amdgcn_cvt_pk_f32_fp8(c3.x, true); \
    f32x2 pd0 = qlo * k0a + qhi * k0b; \
    f32x2 pd1 = qlo * k1a + qhi * k1b; \
    f32x2 pd2 = qlo * k2a + qhi * k2b; \
    f32x2 pd3 = qlo * k3a + qhi * k3b; \
    float p0 = pd0.x + pd0.y, p1 = pd1.x + pd1.y, p2 = pd2.x + pd2.y, p3 = pd3.x + pd3.y; \
    p0 += __shfl_xor(p0, 1); p1 += __shfl_xor(p1, 1); p2 += __shfl_xor(p2, 1); p3 += __shfl_xor(p3, 1); \
    p0 += __shfl_xor(p0, 2); p1 += __shfl_xor(p1, 2); p2 += __shfl_xor(p2, 2); p3 += __shfl_xor(p3, 2); \
    p0 += __shfl_xor(p0, 4); p1 += __shfl_xor(p1, 4); p2 += __shfl_xor(p2, 4); p3 += __shfl_xor(p3, 4); \
    p0 += __shfl_xor(p0, 8); p1 += __shfl_xor(p1, 8); p2 += __shfl_xor(p2, 8); p3 += __shfl_xor(p3, 8); \
    float w0 = __expf(p0 * SC); \
    float w1 = (V1) ? __expf(p1 * SC) : 0.f; \
    float w2 = (V2) ? __expf(p2 * SC) : 0.f; \
    float w3 = (V3) ? __expf(p3 * SC) : 0.f; \
    l += (w0 + w1) + (w2 + w3); \
    f32x2 v0a = __builtin_amdgcn_cvt_pk_f32_fp8(c0.y, false), v0b = __builtin_amdgcn_cvt_pk_f32_fp8(c0.y, true); \
    f32x2 v1a = __builtin_amdgcn_cvt_pk_f32_fp8(c1.y, false), v1b = __builtin_amdgcn_cvt_pk_f32_fp8(c1.y, true); \
    f32x2 v2a = __builtin_amdgcn_cvt_pk_f32_fp8(c2.y, false), v2b = __builtin_amdgcn_cvt_pk_f32_fp8(c2.y, true); \
    f32x2 v3a = __builtin_amdgcn_cvt_pk_f32_fp8(c3.y, false), v3b = __builtin_amdgcn_cvt_pk_f32_fp8(c3.y, true); \
    accA += v0a * w0; accA += v1a * w1; accA += v2a * w2; accA += v3a * w3; \
    accB += v0b * w0; accB += v1b * w1; accB += v2b * w2; accB += v3b * w3; \
} while (0)

__global__ __launch_bounds__(256) void attn_kernel(
    const u16* __restrict__ q, const u8* __restrict__ kv,
    const float* __restrict__ skip,
    const int* __restrict__ row_start, const int* __restrict__ csr_src,
    u16* __restrict__ hout)
{
    __shared__ int s_lds[4][64];     // per-wave private row: no barrier needed
    int wave = threadIdx.x >> 6;
    int lane = threadIdx.x & 63;
    int n = blockIdx.x * 4 + wave;
    if (n >= N_NODES) return;
    ushort4 q4 = ((const ushort4*)(q + (size_t)n * 256))[lane];
    f32x2 qlo = { b2f(q4.x), b2f(q4.y) };
    f32x2 qhi = { b2f(q4.z), b2f(q4.w) };
    const u8* kvl = kv + lane * 8;
    const float SC = 0.0078125f;   // 1/(8*16)
    float l = 0.f;
    f32x2 accA = {0.f, 0.f};
    f32x2 accB = {0.f, 0.f};
    int e0 = row_start[n];
    int deg = row_start[n + 1] - e0;

    for (int base = 0; base < deg; base += 64) {
        int rem = deg - base;
        int m = rem < 64 ? rem : 64;
        int li = lane < m ? lane : m - 1;           // clamp: stay inside this row's edges
        s_lds[wave][lane] = csr_src[e0 + base + li]; // one coalesced load per 64 edges
        int i = 0;
        for (; i + 8 <= m; i += 8) {                // 8 gathers in flight per iter
            int4 sa = *(const int4*)&s_lds[wave][i];
            int4 sb = *(const int4*)&s_lds[wave][i + 4];
            KV_LOAD(c0, sa.x); KV_LOAD(c1, sa.y); KV_LOAD(c2, sa.z); KV_LOAD(c3, sa.w);
            KV_LOAD(d0, sb.x); KV_LOAD(d1, sb.y); KV_LOAD(d2, sb.z); KV_LOAD(d3, sb.w);
            ATTN_BODY(c0, c1, c2, c3, 1, 1, 1);
            ATTN_BODY(d0, d1, d2, d3, 1, 1, 1);
        }
        if (i + 4 <= m) {
            int4 sq = *(const int4*)&s_lds[wave][i];
            KV_LOAD(c0, sq.x); KV_LOAD(c1, sq.y); KV_LOAD(c2, sq.z); KV_LOAD(c3, sq.w);
            ATTN_BODY(c0, c1, c2, c3, 1, 1, 1);
            i += 4;
        }
        if (i < m) {                                  // tail: 1..3 edges, masked quad
            int4 sq = *(const int4*)&s_lds[wave][i];  // i%4==0, i<=60: aligned, in-bounds
            int rem2 = m - i;
            int sB = rem2 > 1 ? sq.y : sq.x;
            int sC = rem2 > 2 ? sq.z : sq.x;
            KV_LOAD(c0, sq.x); KV_LOAD(c1, sB); KV_LOAD(c2, sC); KV_LOAD(c3, sq.x);
            ATTN_BODY(c0, c1, c2, c3, rem2 > 1, rem2 > 2, 0);
        }
    }

    float inv = l > 0.f ? 1.f / l : 0.f;
    float a0 = accA.x * inv, a1 = accA.y * inv;
    float a2 = accB.x * inv, a3 = accB.y * inv;
    a0 += __shfl_xor(a0, 16); a0 += __shfl_xor(a0, 32);
    a1 += __shfl_xor(a1, 16); a1 += __shfl_xor(a1, 32);
    a2 += __shfl_xor(a2, 16); a2 += __shfl_xor(a2, 32);
    a3 += __shfl_xor(a3, 16); a3 += __shfl_xor(a3, 32);
    if ((lane >> 4) == 0) {
        const float OS = 0.015625f;  // 0.25 (head mean) * 1/16 (v scale)
        float4 sk = ((const float4*)(skip + (size_t)n * 64))[lane];
        ushort4 o;
        o.x = f2b(elu_f(OS * a0 + sk.x));
        o.y = f2b(elu_f(OS * a1 + sk.y));
        o.z = f2b(elu_f(OS * a2 + sk.z));
        o.w = f2b(elu_f(OS * a3 + sk.w));
        ((ushort4*)(hout + (size_t)n * 64))[lane] = o;
    }
}

// ---------------- Output MLP: 64->64 elu (MFMA) ->32 elu (MFMA) ->8 (VALU),
// bf16 h input ----------------
__global__ __launch_bounds__(256) void mlp_kernel(const u16* __restrict__ h,
    const float* __restrict__ w1, const float* __restrict__ b1,
    const float* __restrict__ w2, const float* __restrict__ b2,
    const float* __restrict__ w3, const float* __restrict__ b3,
    float* __restrict__ out)
{
    __shared__ u16 hs[64 * 72];
    __shared__ u16 w1s[64 * 72];
    __shared__ u16 t1s[64 * 72];
    __shared__ u16 w2s[32 * 72];
    __shared__ float t2s[64 * 33];
    __shared__ float w3s[8 * 33];
    __shared__ float b1s[64], b2s[32], b3s[8];
    int t = threadIdx.x;
    int m0 = blockIdx.x * 64;

    #pragma unroll
    for (int it = 0; it < 2; ++it) {
        int p = t + it * 256; int row = p >> 3, kc = (p & 7) * 8;
        uint4 val = make_uint4(0u, 0u, 0u, 0u);
        if (m0 + row < N_NODES) val = *(const uint4*)(h + (size_t)(m0 + row) * 64 + kc);
        *(uint4*)&hs[row * 72 + kc] = val;
    }
    #pragma unroll
    for (int r = 0; r < 4; ++r) {
        int p = t + r * 256; int row = p >> 4, kc = (p & 15) * 4;
        float4 val = *(const float4*)(w1 + row * 64 + kc);
        ushort4 u; u.x = f2b(val.x); u.y = f2b(val.y); u.z = f2b(val.z); u.w = f2b(val.w);
        *(ushort4*)&w1s[row * 72 + kc] = u;
    }
    #pragma unroll
    for (int r = 0; r < 2; ++r) {
        int p = t + r * 256; int row = p >> 4, kc = (p & 15) * 4;
        float4 val = *(const float4*)(w2 + row * 64 + kc);
        ushort4 u; u.x = f2b(val.x); u.y = f2b(val.y); u.z = f2b(val.z); u.w = f2b(val.w);
        *(ushort4*)&w2s[row * 72 + kc] = u;
    }
    if (t < 8 * 32) { int r = t >> 5, c = t & 31; w3s[r * 33 + c] = w3[t]; }
    if (t < 64) b1s[t] = b1[t];
    if (t >= 64 && t < 96) b2s[t - 64] = b2[t - 64];
    if (t >= 96 && t < 104) b3s[t - 96] = b3[t - 96];
    __syncthreads();

    int wave = t >> 6, lane = t & 63;
    int lrow = lane & 15, quad = lane >> 4;
    int m_off = wave * 16;

    {
        bf16x8 a0 = *(const bf16x8*)&hs[(m_off + lrow) * 72 + quad * 8];
        bf16x8 a1 = *(const bf16x8*)&hs[(m_off + lrow) * 72 + 32 + quad * 8];
        #pragma unroll
        for (int nsub = 0; nsub < 4; ++nsub) {
            bf16x8 b0 = *(const bf16x8*)&w1s[(nsub * 16 + lrow) * 72 + quad * 8];
            bf16x8 b1v = *(const bf16x8*)&w1s[(nsub * 16 + lrow) * 72 + 32 + quad * 8];
            f32x4 acc = {0.f, 0.f, 0.f, 0.f};
            acc = __builtin_amdgcn_mfma_f32_16x16x32_bf16(a0, b0, acc, 0, 0, 0);
            acc = __builtin_amdgcn_mfma_f32_16x16x32_bf16(a1, b1v, acc, 0, 0, 0);
            int col = nsub * 16 + lrow;
            float bias = b1s[col];
            #pragma unroll
            for (int r = 0; r < 4; ++r) {
                int row = m_off + quad * 4 + r;
                t1s[row * 72 + col] = f2b(elu_f(acc[r] + bias));
            }
        }
    }
    __syncthreads();

    {
        bf16x8 a0 = *(const bf16x8*)&t1s[(m_off + lrow) * 72 + quad * 8];
        bf16x8 a1 = *(const bf16x8*)&t1s[(m_off + lrow) * 72 + 32 + quad * 8];
        #pragma unroll
        for (int nsub = 0; nsub < 2; ++nsub) {
            bf16x8 b0 = *(const bf16x8*)&w2s[(nsub * 16 + lrow) * 72 + quad * 8];
            bf16x8 b1v = *(const bf16x8*)&w2s[(nsub * 16 + lrow) * 72 + 32 + quad * 8];
            f32x4 acc = {0.f, 0.f, 0.f, 0.f};
            acc = __builtin_amdgcn_mfma_f32_16x16x32_bf16(a0, b0, acc, 0, 0, 0);
            acc = __builtin_amdgcn_mfma_f32_16x16x32_bf16(a1, b1v, acc, 0, 0, 0);
            int col = nsub * 16 + lrow;
            float bias = b2s[col];
            #pragma unroll
            for (int r = 0; r < 4; ++r) {
                int row = m_off + quad * 4 + r;
                t2s[row * 33 + col] = elu_f(acc[r] + bias);
            }
        }
    }
    __syncthreads();

    #pragma unroll
    for (int r = 0; r < 2; ++r) {
        int idx = t + r * 256;
        int node = idx >> 3, j = idx & 7;
        int row = m0 + node;
        if (row < N_NODES) {
            float acc = b3s[j];
            #pragma unroll
            for (int kk = 0; kk < 32; ++kk) acc += t2s[node * 33 + kk] * w3s[j * 33 + kk];
            out[(size_t)row * 8 + j] = acc;
        }
    }
}

extern "C" void kernel_launch(void* const* d_in, const int* in_sizes, int n_in,
                              void* d_out, int out_size, void* d_ws, size_t ws_size,
                              hipStream_t stream) {
    (void)in_sizes; (void)n_in; (void)out_size; (void)ws_size;
    const float* x   = (const float*)d_in[0];
    const int* ei    = (const int*)d_in[1];
    const float* ew1 = (const float*)d_in[2];
    const float* eb1 = (const float*)d_in[3];
    const float* ew2 = (const float*)d_in[4];
    const float* eb2 = (const float*)d_in[5];
    const float* Wq  = (const float*)d_in[6];
    const float* bq  = (const float*)d_in[7];
    const float* Wk  = (const float*)d_in[8];
    const float* bk  = (const float*)d_in[9];
    const float* Wv  = (const float*)d_in[10];
    const float* bv  = (const float*)d_in[11];
    const float* Wsk = (const float*)d_in[12];
    const float* bsk = (const float*)d_in[13];
    const float* ow1 = (const float*)d_in[14];
    const float* ob1 = (const float*)d_in[15];
    const float* ow2 = (const float*)d_in[16];
    const float* ob2 = (const float*)d_in[17];
    const float* ow3 = (const float*)d_in[18];
    const float* ob3 = (const float*)d_in[19];

    char* ws = (char*)d_ws;
    size_t off = 0;
    auto alloc = [&](size_t bytes) -> void* {
        void* p = ws + off;
        off += (bytes + 255) & ~(size_t)255;
        return p;
    };
    u16*   h0    = (u16*)  alloc((size_t)N_NODES * 64 * 2);
    u16*   h1    = (u16*)  alloc((size_t)N_NODES * 64 * 2);
    u16*   q     = (u16*)  alloc((size_t)N_NODES * 256 * 2);
    u8*    kv    = (u8*)   alloc((size_t)N_NODES * 512);
    float* skp   = (float*)alloc((size_t)N_NODES * 64 * 4);
    u16*   w16   = (u16*)  alloc((size_t)212992 * 2);
    int*   cnt   = (int*)  alloc((size_t)N_NODES * 4);   // cnt+cursor contiguous (each padded to 200192)
    int*   cursor= (int*)  alloc((size_t)N_NODES * 4);
    int*   rowst = (int*)  alloc((size_t)(N_NODES + 1) * 4);
    int*   csr   = (int*)  alloc((size_t)N_EDGES * 4);
    int*   bsum  = (int*)  alloc(512);
    int*   flag  = (int*)  alloc(256);

    u16* wq16  = w16;
    u16* wk16  = w16 + 65536;
    u16* wv16  = w16 + 131072;
    u16* wsk16 = w16 + 196608;

    const int NB = (N_NODES + 511) / 512;   // 98 scan blocks

    // zero cnt+cursor in one memset (adjacent 200192-byte padded allocations)
    hipMemsetAsync(cnt, 0, 2 * 200192, stream);
    detect_kernel<<<1, 256, 0, stream>>>(ei, flag);
    wcvt_kernel<<<208, 256, 0, stream>>>(Wq, Wk, Wv, Wsk, w16);
    hist_kernel<<<(N_EDGES + 255) / 256, 256, 0, stream>>>(ei, flag, cnt);
    scan1_kernel<<<NB, 512, 0, stream>>>(cnt, rowst, bsum);
    scan2_kernel<<<1, 128, 0, stream>>>(bsum, rowst);
    scan3_kernel<<<NB, 512, 0, stream>>>(rowst, bsum);
    scatter_kernel<<<(N_EDGES + 255) / 256, 256, 0, stream>>>(ei, flag, rowst, cursor, csr);

    encoder_kernel<<<(N_NODES + 63) / 64, 256, 0, stream>>>(x, ew1, eb1, ew2, eb2, h0);

    u16* hin = h0;
    u16* hout = h1;
    for (int l = 0; l < 4; ++l) {
        proj_kernel<<<(N_NODES + 63) / 64, 256, 0, stream>>>(hin, wq16, wk16, wv16, wsk16,
                                                             bq, bk, bv, bsk, l, q, kv, skp);
        attn_kernel<<<(N_NODES + 3) / 4, 256, 0, stream>>>(q, kv, skp, rowst, csr, hout);
        u16* tmp = hin; hin = hout; hout = tmp;
    }

    mlp_kernel<<<(N_NODES + 63) / 64, 256, 0, stream>>>(hin, ow1, ob1, ow2, ob2, ow3, ob3, (float*)d_out);
}

// Round 5
// 456.059 us; speedup vs baseline: 1.5280x; 1.1480x over previous
//
#include <hip/hip_runtime.h>
#include <hip/hip_bf16.h>

#define N_NODES 50000
#define N_EDGES 500000
constexpr int HID = 64;
constexpr int HC  = 256;   // HEADS*HID

typedef unsigned short u16;
typedef unsigned char u8;
typedef __attribute__((ext_vector_type(8))) __bf16 bf16x8;
typedef __attribute__((ext_vector_type(4))) float f32x4;
typedef __attribute__((ext_vector_type(2))) float f32x2;

__device__ __forceinline__ float b2f(u16 u) {
    union { unsigned int i; float f; } c; c.i = ((unsigned int)u) << 16; return c.f;
}
__device__ __forceinline__ u16 f2b(float f) {
    union { float f; unsigned int i; } c; c.f = f;
    unsigned int x = c.i;
    unsigned int lsb = (x >> 16) & 1u;
    x += 0x7fffu + lsb;
    return (u16)(x >> 16);
}
__device__ __forceinline__ float elu_f(float x) { return x > 0.f ? x : expm1f(x); }

// h is stored bf16 (u16) everywhere: every consumer converts to bf16 before
// use anyway, so storing bf16 at the producer is bit-identical downstream.
// kv fp8 layout (scale 16, e4m3): group g (8B) = [k ch 4g..4g+3][v ch 4g..4g+3]

// ---------------- edge_index layout detect (int32 vs int64) ----------------
__global__ __launch_bounds__(256) void detect_kernel(const int* __restrict__ ei, int* __restrict__ flag) {
    __shared__ int s[4];
    int t = threadIdx.x;
    int nz = ei[2 * t + 1] != 0;
    unsigned long long m = __ballot(nz);
    if ((t & 63) == 0) s[t >> 6] = (m != 0ull) ? 1 : 0;
    __syncthreads();
    if (t == 0) flag[0] = s[0] | s[1] | s[2] | s[3];   // 1 => int32 layout
}

// ---------------- weight pre-conversion fp32 -> bf16 (once) ----------------
__global__ __launch_bounds__(256) void wcvt_kernel(const float* __restrict__ Wq, const float* __restrict__ Wk,
                                                   const float* __restrict__ Wv, const float* __restrict__ Wsk,
                                                   u16* __restrict__ w16) {
    int i = blockIdx.x * 256 + threadIdx.x;   // float4 index
    if (i >= 53248) return;
    const float* src; int off;
    if (i < 16384)      { src = Wq;  off = i; }
    else if (i < 32768) { src = Wk;  off = i - 16384; }
    else if (i < 49152) { src = Wv;  off = i - 32768; }
    else                { src = Wsk; off = i - 49152; }
    float4 v = ((const float4*)src)[off];
    ushort4 u; u.x = f2b(v.x); u.y = f2b(v.y); u.z = f2b(v.z); u.w = f2b(v.w);
    ((ushort4*)w16)[i] = u;
}

// ---------------- CSR build (counting sort by dst) ----------------
__global__ __launch_bounds__(256) void hist_kernel(const int* __restrict__ ei, const int* __restrict__ flag,
                                                   int* __restrict__ cnt) {
    int e = blockIdx.x * 256 + threadIdx.x;
    if (e < N_EDGES) {
        int d = flag[0] ? ei[N_EDGES + e] : ei[2 * N_EDGES + 2 * e];
        atomicAdd(&cnt[d], 1);
    }
}

__global__ __launch_bounds__(512) void scan1_kernel(const int* __restrict__ cnt,
                                                    int* __restrict__ row_start, int* __restrict__ bsum) {
    __shared__ int sc[512];
    int t = threadIdx.x;
    int i = blockIdx.x * 512 + t;
    int v = (i < N_NODES) ? cnt[i] : 0;
    sc[t] = v;
    __syncthreads();
    for (int off = 1; off < 512; off <<= 1) {
        int u = (t >= off) ? sc[t - off] : 0;
        __syncthreads();
        sc[t] += u;
        __syncthreads();
    }
    if (i < N_NODES) row_start[i] = sc[t] - v;
    if (t == 511) bsum[blockIdx.x] = sc[511];
}

__global__ __launch_bounds__(128) void scan2_kernel(int* __restrict__ bsum, int* __restrict__ row_start) {
    __shared__ int sc[128];
    const int NB = (N_NODES + 511) / 512;  // 98
    int t = threadIdx.x;
    int v = (t < NB) ? bsum[t] : 0;
    sc[t] = v;
    __syncthreads();
    for (int off = 1; off < 128; off <<= 1) {
        int u = (t >= off) ? sc[t - off] : 0;
        __syncthreads();
        sc[t] += u;
        __syncthreads();
    }
    if (t < NB) bsum[t] = sc[t] - v;
    if (t == 127) row_start[N_NODES] = sc[127];
}

__global__ __launch_bounds__(512) void scan3_kernel(int* __restrict__ row_start, const int* __restrict__ bsum) {
    int i = blockIdx.x * 512 + threadIdx.x;
    if (i < N_NODES) row_start[i] += bsum[blockIdx.x];
}

__global__ __launch_bounds__(256) void scatter_kernel(const int* __restrict__ ei, const int* __restrict__ flag,
                                const int* __restrict__ row_start, int* __restrict__ cursor,
                                int* __restrict__ csr_src) {
    int e = blockIdx.x * 256 + threadIdx.x;
    if (e < N_EDGES) {
        int isI32 = flag[0];
        int s = isI32 ? ei[e] : ei[2 * e];
        int d = isI32 ? ei[N_EDGES + e] : ei[2 * N_EDGES + 2 * e];
        int pos = row_start[d] + atomicAdd(&cursor[d], 1);
        csr_src[pos] = s;
    }
}

// ---------------- Encoder: 8->64 elu (VALU) -> 64->64 elu (MFMA), bf16 out ----------------
__global__ __launch_bounds__(256) void encoder_kernel(const float* __restrict__ x,
                               const float* __restrict__ w1, const float* __restrict__ b1,
                               const float* __restrict__ w2, const float* __restrict__ b2,
                               u16* __restrict__ h) {
    __shared__ float xs[64 * 9];
    __shared__ float w1s[64 * 9];
    __shared__ u16 t1s[64 * 72];
    __shared__ u16 w2s[64 * 72];
    __shared__ float b1s[64], b2s[64];
    int t = threadIdx.x;
    int m0 = blockIdx.x * 64;

    if (t < 128) {
        int row = t >> 1, c = (t & 1) * 4;
        float4 val = make_float4(0.f, 0.f, 0.f, 0.f);
        if (m0 + row < N_NODES) val = *(const float4*)(x + (size_t)(m0 + row) * 8 + c);
        *(float4*)&xs[row * 9 + c] = val;
    }
    if (t >= 128 && t < 256) {
        int p = t - 128;
        int row = p >> 1, c = (p & 1) * 4;
        float4 val = *(const float4*)(w1 + row * 8 + c);
        *(float4*)&w1s[row * 9 + c] = val;
    }
    #pragma unroll
    for (int r = 0; r < 4; ++r) {
        int p = t + r * 256; int row = p >> 4, kc = (p & 15) * 4;
        float4 val = *(const float4*)(w2 + row * 64 + kc);
        ushort4 u; u.x = f2b(val.x); u.y = f2b(val.y); u.z = f2b(val.z); u.w = f2b(val.w);
        *(ushort4*)&w2s[row * 72 + kc] = u;
    }
    if (t < 64) { b1s[t] = b1[t]; b2s[t] = b2[t]; }
    __syncthreads();

    {
        int j = t & 63, sub = t >> 6;
        #pragma unroll
        for (int g = 0; g < 16; ++g) {
            int node = g * 4 + sub;
            float acc = b1s[j];
            #pragma unroll
            for (int m = 0; m < 8; ++m) acc += xs[node * 9 + m] * w1s[j * 9 + m];
            t1s[node * 72 + j] = f2b(elu_f(acc));
        }
    }
    __syncthreads();

    int wave = t >> 6, lane = t & 63;
    int lrow = lane & 15, quad = lane >> 4;
    int m_off = wave * 16;
    bf16x8 a0 = *(const bf16x8*)&t1s[(m_off + lrow) * 72 + quad * 8];
    bf16x8 a1 = *(const bf16x8*)&t1s[(m_off + lrow) * 72 + 32 + quad * 8];
    #pragma unroll
    for (int nsub = 0; nsub < 4; ++nsub) {
        bf16x8 b0 = *(const bf16x8*)&w2s[(nsub * 16 + lrow) * 72 + quad * 8];
        bf16x8 b1v = *(const bf16x8*)&w2s[(nsub * 16 + lrow) * 72 + 32 + quad * 8];
        f32x4 acc = {0.f, 0.f, 0.f, 0.f};
        acc = __builtin_amdgcn_mfma_f32_16x16x32_bf16(a0, b0, acc, 0, 0, 0);
        acc = __builtin_amdgcn_mfma_f32_16x16x32_bf16(a1, b1v, acc, 0, 0, 0);
        int col = nsub * 16 + lrow;
        float bias = b2s[col];
        #pragma unroll
        for (int r = 0; r < 4; ++r) {
            int row = m0 + m_off + quad * 4 + r;
            if (row < N_NODES) h[(size_t)row * 64 + col] = f2b(elu_f(acc[r] + bias));
        }
    }
}

// ---------------- Projection v3: double-buffered weight staging with
// issue-early / LDS-write-late (T14) so each tile's L2 load latency hides
// under the previous tile's MFMA + flush. Output staging unchanged. ----------------
__global__ __launch_bounds__(256) void proj_kernel(const u16* __restrict__ h,
    const u16* __restrict__ wq16, const u16* __restrict__ wk16,
    const u16* __restrict__ wv16, const u16* __restrict__ wsk16,
    const float* __restrict__ bq, const float* __restrict__ bk,
    const float* __restrict__ bv, const float* __restrict__ bsk,
    int layer,
    u16* __restrict__ q, u8* __restrict__ kv, float* __restrict__ skip)
{
    __shared__ u16 wsA[64 * 72];         // double-buffered weight tile (also h stage)
    __shared__ u16 wsB[64 * 72];
    __shared__ float pool[64 * 68];      // 17408 B: qst u16[64*72] / kvst u8[64*144] / skst f32[64*68]
    u16* qst  = (u16*)pool;
    u8*  kvst = (u8*)pool;
    float* skst = pool;

    int t = threadIdx.x;
    int m0 = blockIdx.x * 64;
    int wave = t >> 6, lane = t & 63;
    int lrow = lane & 15, quad = lane >> 4;
    int nl = wave * 16 + lrow;          // node local index owned by this lane

    const u16* Wq16  = wq16  + (size_t)layer * HC * HID;
    const u16* Wk16  = wk16  + (size_t)layer * HC * HID;
    const u16* Wv16  = wv16  + (size_t)layer * HC * HID;
    const u16* Wsk16 = wsk16 + (size_t)layer * HID * HID;
    const float* bqL  = bq  + layer * HC;
    const float* bkL  = bk  + layer * HC;
    const float* bvL  = bv  + layer * HC;
    const float* bskL = bsk + layer * HID;

    // ---- prologue: stage h tile through wsA, extract per-lane fragment ----
    #pragma unroll
    for (int it = 0; it < 2; ++it) {
        int p = t + it * 256; int row = p >> 3, kc = (p & 7) * 8;
        uint4 val = make_uint4(0u, 0u, 0u, 0u);
        if (m0 + row < N_NODES) val = *(const uint4*)(h + (size_t)(m0 + row) * 64 + kc);
        *(uint4*)&wsA[row * 72 + kc] = val;
    }
    __syncthreads();
    bf16x8 a0 = *(const bf16x8*)&wsA[(wave * 16 + lrow) * 72 + quad * 8];
    bf16x8 a1 = *(const bf16x8*)&wsA[(wave * 16 + lrow) * 72 + 32 + quad * 8];

    auto stageIssue = [&](const u16* W, int cb, uint4& r0, uint4& r1) {
        const u16* sp = W + (size_t)(cb + (t >> 3)) * 64 + (t & 7) * 8;
        r0 = *(const uint4*)sp;
        r1 = *(const uint4*)(sp + 2048);    // +32 rows
    };
    auto stageWrite = [&](u16* buf, uint4 r0, uint4 r1) {
        int row = t >> 3, kc = (t & 7) * 8;
        *(uint4*)&buf[row * 72 + kc] = r0;
        *(uint4*)&buf[(row + 32) * 72 + kc] = r1;
    };

    auto computeQ = [&](int ct, const u16* BUF) {
        #pragma unroll
        for (int nsub = 0; nsub < 4; ++nsub) {
            bf16x8 w0 = *(const bf16x8*)&BUF[(nsub * 16 + lrow) * 72 + quad * 8];
            bf16x8 w1 = *(const bf16x8*)&BUF[(nsub * 16 + lrow) * 72 + 32 + quad * 8];
            f32x4 acc = {0.f, 0.f, 0.f, 0.f};
            acc = __builtin_amdgcn_mfma_f32_16x16x32_bf16(w0, a0, acc, 0, 0, 0);
            acc = __builtin_amdgcn_mfma_f32_16x16x32_bf16(w1, a1, acc, 0, 0, 0);
            float4 b4 = *(const float4*)(bqL + ct * 64 + nsub * 16 + quad * 4);
            ushort4 o;
            o.x = f2b(acc[0] + b4.x); o.y = f2b(acc[1] + b4.y);
            o.z = f2b(acc[2] + b4.z); o.w = f2b(acc[3] + b4.w);
            *(ushort4*)&qst[nl * 72 + nsub * 16 + quad * 4] = o;
        }
    };
    auto computeKV = [&](int ct, const u16* BUF, const float* bias, int voff) {
        #pragma unroll
        for (int nsub = 0; nsub < 4; ++nsub) {
            bf16x8 w0 = *(const bf16x8*)&BUF[(nsub * 16 + lrow) * 72 + quad * 8];
            bf16x8 w1 = *(const bf16x8*)&BUF[(nsub * 16 + lrow) * 72 + 32 + quad * 8];
            f32x4 acc = {0.f, 0.f, 0.f, 0.f};
            acc = __builtin_amdgcn_mfma_f32_16x16x32_bf16(w0, a0, acc, 0, 0, 0);
            acc = __builtin_amdgcn_mfma_f32_16x16x32_bf16(w1, a1, acc, 0, 0, 0);
            float4 b4 = *(const float4*)(bias + ct * 64 + nsub * 16 + quad * 4);
            float f0 = (acc[0] + b4.x) * 16.f, f1 = (acc[1] + b4.y) * 16.f;
            float f2v = (acc[2] + b4.z) * 16.f, f3v = (acc[3] + b4.w) * 16.f;
            int pk = __builtin_amdgcn_cvt_pk_fp8_f32(f0, f1, 0, false);
            pk = __builtin_amdgcn_cvt_pk_fp8_f32(f2v, f3v, pk, true);
            int g = nsub * 4 + quad;
            *(unsigned int*)&kvst[nl * 144 + g * 8 + voff] = (unsigned int)pk;
        }
    };
    auto computeSK = [&](const u16* BUF) {
        #pragma unroll
        for (int nsub = 0; nsub < 4; ++nsub) {
            bf16x8 w0 = *(const bf16x8*)&BUF[(nsub * 16 + lrow) * 72 + quad * 8];
            bf16x8 w1 = *(const bf16x8*)&BUF[(nsub * 16 + lrow) * 72 + 32 + quad * 8];
            f32x4 acc = {0.f, 0.f, 0.f, 0.f};
            acc = __builtin_amdgcn_mfma_f32_16x16x32_bf16(w0, a0, acc, 0, 0, 0);
            acc = __builtin_amdgcn_mfma_f32_16x16x32_bf16(w1, a1, acc, 0, 0, 0);
            float4 b4 = *(const float4*)(bskL + nsub * 16 + quad * 4);
            float4 o;
            o.x = acc[0] + b4.x; o.y = acc[1] + b4.y;
            o.z = acc[2] + b4.z; o.w = acc[3] + b4.w;
            *(float4*)&skst[nl * 68 + nsub * 16 + quad * 4] = o;
        }
    };
    auto flushQ = [&](int ct) {
        #pragma unroll
        for (int it = 0; it < 2; ++it) {
            int p = t + it * 256; int row = p >> 3, ch = p & 7;
            int grow = m0 + row;
            if (grow < N_NODES)
                *(uint4*)(q + (size_t)grow * 256 + ct * 64 + ch * 8) = *(const uint4*)&qst[row * 72 + ch * 8];
        }
    };
    auto flushKV = [&](int ct) {
        #pragma unroll
        for (int it = 0; it < 2; ++it) {
            int p = t + it * 256; int row = p >> 3, ch = p & 7;
            int grow = m0 + row;
            if (grow < N_NODES)
                *(uint4*)(kv + (size_t)grow * 512 + ct * 128 + ch * 16) = *(const uint4*)&kvst[row * 144 + ch * 16];
        }
    };

    // stage Q0 -> wsB (wsA holds h; no conflict), then pipeline.
    {
        uint4 r0, r1;
        stageIssue(Wq16, 0, r0, r1);
        stageWrite(wsB, r0, r1);
    }
    __syncthreads();

    uint4 r0, r1;
    // tiles: Q0(B) Q1(A) Q2(B) Q3(A) K0(B) V0(A) K1(B) V1(A) K2(B) V2(A) K3(B) V3(A) SK(B)
    stageIssue(Wq16, 64, r0, r1);  computeQ(0, wsB);          __syncthreads(); flushQ(0);  stageWrite(wsA, r0, r1); __syncthreads();
    stageIssue(Wq16, 128, r0, r1); computeQ(1, wsA);          __syncthreads(); flushQ(1);  stageWrite(wsB, r0, r1); __syncthreads();
    stageIssue(Wq16, 192, r0, r1); computeQ(2, wsB);          __syncthreads(); flushQ(2);  stageWrite(wsA, r0, r1); __syncthreads();
    stageIssue(Wk16, 0, r0, r1);   computeQ(3, wsA);          __syncthreads(); flushQ(3);  stageWrite(wsB, r0, r1); __syncthreads();
    stageIssue(Wv16, 0, r0, r1);   computeKV(0, wsB, bkL, 0); __syncthreads();             stageWrite(wsA, r0, r1); __syncthreads();
    stageIssue(Wk16, 64, r0, r1);  computeKV(0, wsA, bvL, 4); __syncthreads(); flushKV(0); stageWrite(wsB, r0, r1); __syncthreads();
    stageIssue(Wv16, 64, r0, r1);  computeKV(1, wsB, bkL, 0); __syncthreads();             stageWrite(wsA, r0, r1); __syncthreads();
    stageIssue(Wk16, 128, r0, r1); computeKV(1, wsA, bvL, 4); __syncthreads(); flushKV(1); stageWrite(wsB, r0, r1); __syncthreads();
    stageIssue(Wv16, 128, r0, r1); computeKV(2, wsB, bkL, 0); __syncthreads();             stageWrite(wsA, r0, r1); __syncthreads();
    stageIssue(Wk16, 192, r0, r1); computeKV(2, wsA, bvL, 4); __syncthreads(); flushKV(2); stageWrite(wsB, r0, r1); __syncthreads();
    stageIssue(Wv16, 192, r0, r1); computeKV(3, wsB, bkL, 0); __syncthreads();             stageWrite(wsA, r0, r1); __syncthreads();
    stageIssue(Wsk16, 0, r0, r1);  computeKV(3, wsA, bvL, 4); __syncthreads(); flushKV(3); stageWrite(wsB, r0, r1); __syncthreads();

    // ---- last phase: skip tile (fp32 out) ----
    computeSK(wsB);
    __syncthreads();
    {
        int row = t >> 2, c0 = (t & 3) * 16;
        int grow = m0 + row;
        if (grow < N_NODES) {
            #pragma unroll
            for (int j = 0; j < 4; ++j)
                *(float4*)(skip + (size_t)grow * 64 + c0 + j * 4) = *(const float4*)&skst[row * 68 + c0 + j * 4];
        }
    }
}

// ---------------- Attention v3 (proven 51 us): LDS-broadcast CSR, 4-deep
// quad pipeline, packed f32x2 math, bf16 h output. ----------------
#define ATTN_QUAD(S0q, S1q, S2q, S3q, V1, V2, V3) do { \
    uint2 c0 = *(const uint2*)(kvl + (size_t)(unsigned)(S0q) * 512); \
    uint2 c1 = *(const uint2*)(kvl + (size_t)(unsigned)(S1q) * 512); \
    uint2 c2 = *(const uint2*)(kvl + (size_t)(unsigned)(S2q) * 512); \
    uint2 c3 = *(const uint2*)(kvl + (size_t)(unsigned)(S3q) * 512); \
    f32x2 k0a = __builtin_amdgcn_cvt_pk_f32_fp8(c0.x, false), k0b = __builtin_amdgcn_cvt_pk_f32_fp8(c0.x, true); \
    f32x2 k1a = __builtin_amdgcn_cvt_pk_f32_fp8(c1.x, false), k1b = __builtin_amdgcn_cvt_pk_f32_fp8(c1.x, true); \
    f32x2 k2a = __builtin_amdgcn_cvt_pk_f32_fp8(c2.x, false), k2b = __builtin_amdgcn_cvt_pk_f32_fp8(c2.x, true); \
    f32x2 k3a = __builtin_amdgcn_cvt_pk_f32_fp8(c3.x, false), k3b = __builtin_amdgcn_cvt_pk_f32_fp8(c3.x, true); \
    f32x2 pd0 = qlo * k0a + qhi * k0b; \
    f32x2 pd1 = qlo * k1a + qhi * k1b; \
    f32x2 pd2 = qlo * k2a + qhi * k2b; \
    f32x2 pd3 = qlo * k3a + qhi * k3b; \
    float p0 = pd0.x + pd0.y, p1 = pd1.x + pd1.y, p2 = pd2.x + pd2.y, p3 = pd3.x + pd3.y; \
    p0 += __shfl_xor(p0, 1); p1 += __shfl_xor(p1, 1); p2 += __shfl_xor(p2, 1); p3 += __shfl_xor(p3, 1); \
    p0 += __shfl_xor(p0, 2); p1 += __shfl_xor(p1, 2); p2 += __shfl_xor(p2, 2); p3 += __shfl_xor(p3, 2); \
    p0 += __shfl_xor(p0, 4); p1 += __shfl_xor(p1, 4); p2 += __shfl_xor(p2, 4); p3 += __shfl_xor(p3, 4); \
    p0 += __shfl_xor(p0, 8); p1 += __shfl_xor(p1, 8); p2 += __shfl_xor(p2, 8); p3 += __shfl_xor(p3, 8); \
    float w0 = __expf(p0 * SC); \
    float w1 = (V1) ? __expf(p1 * SC) : 0.f; \
    float w2 = (V2) ? __expf(p2 * SC) : 0.f; \
    float w3 = (V3) ? __expf(p3 * SC) : 0.f; \
    l += (w0 + w1) + (w2 + w3); \
    f32x2 v0a = __builtin_amdgcn_cvt_pk_f32_fp8(c0.y, false), v0b = __builtin_amdgcn_cvt_pk_f32_fp8(c0.y, true); \
    f32x2 v1a = __builtin_amdgcn_cvt_pk_f32_fp8(c1.y, false), v1b = __builtin_amdgcn_cvt_pk_f32_fp8(c1.y, true); \
    f32x2 v2a = __builtin_amdgcn_cvt_pk_f32_fp8(c2.y, false), v2b = __builtin_amdgcn_cvt_pk_f32_fp8(c2.y, true); \
    f32x2 v3a = __builtin_amdgcn_cvt_pk_f32_fp8(c3.y, false), v3b = __builtin_amdgcn_cvt_pk_f32_fp8(c3.y, true); \
    accA += v0a * w0; accA += v1a * w1; accA += v2a * w2; accA += v3a * w3; \
    accB += v0b * w0; accB += v1b * w1; accB += v2b * w2; accB += v3b * w3; \
} while (0)

__global__ __launch_bounds__(256) void attn_kernel(
    const u16* __restrict__ q, const u8* __restrict__ kv,
    const float* __restrict__ skip,
    const int* __restrict__ row_start, const int* __restrict__ csr_src,
    u16* __restrict__ hout)
{
    __shared__ int s_lds[4][64];     // per-wave private row: no barrier needed
    int wave = threadIdx.x >> 6;
    int lane = threadIdx.x & 63;
    int n = blockIdx.x * 4 + wave;
    if (n >= N_NODES) return;
    ushort4 q4 = ((const ushort4*)(q + (size_t)n * 256))[lane];
    f32x2 qlo = { b2f(q4.x), b2f(q4.y) };
    f32x2 qhi = { b2f(q4.z), b2f(q4.w) };
    const u8* kvl = kv + lane * 8;
    const float SC = 0.0078125f;   // 1/(8*16)
    float l = 0.f;
    f32x2 accA = {0.f, 0.f};
    f32x2 accB = {0.f, 0.f};
    int e0 = row_start[n];
    int deg = row_start[n + 1] - e0;

    for (int base = 0; base < deg; base += 64) {
        int rem = deg - base;
        int m = rem < 64 ? rem : 64;
        int li = lane < m ? lane : m - 1;           // clamp: stay inside this row's edges
        s_lds[wave][lane] = csr_src[e0 + base + li]; // one coalesced load per 64 edges
        int i = 0;
        for (; i + 4 <= m; i += 4) {
            int4 sq = *(const int4*)&s_lds[wave][i];  // uniform addr -> LDS broadcast
            ATTN_QUAD(sq.x, sq.y, sq.z, sq.w, 1, 1, 1);
        }
        if (i < m) {                                  // tail: 1..3 edges, masked quad
            int4 sq = *(const int4*)&s_lds[wave][i];  // i%4==0, i<=60: aligned, in-bounds
            int rem2 = m - i;
            int sB = rem2 > 1 ? sq.y : sq.x;
            int sC = rem2 > 2 ? sq.z : sq.x;
            ATTN_QUAD(sq.x, sB, sC, sq.x, rem2 > 1, rem2 > 2, 0);
        }
    }

    float inv = l > 0.f ? 1.f / l : 0.f;
    float a0 = accA.x * inv, a1 = accA.y * inv;
    float a2 = accB.x * inv, a3 = accB.y * inv;
    a0 += __shfl_xor(a0, 16); a0 += __shfl_xor(a0, 32);
    a1 += __shfl_xor(a1, 16); a1 += __shfl_xor(a1, 32);
    a2 += __shfl_xor(a2, 16); a2 += __shfl_xor(a2, 32);
    a3 += __shfl_xor(a3, 16); a3 += __shfl_xor(a3, 32);
    if ((lane >> 4) == 0) {
        const float OS = 0.015625f;  // 0.25 (head mean) * 1/16 (v scale)
        float4 sk = ((const float4*)(skip + (size_t)n * 64))[lane];
        ushort4 o;
        o.x = f2b(elu_f(OS * a0 + sk.x));
        o.y = f2b(elu_f(OS * a1 + sk.y));
        o.z = f2b(elu_f(OS * a2 + sk.z));
        o.w = f2b(elu_f(OS * a3 + sk.w));
        ((ushort4*)(hout + (size_t)n * 64))[lane] = o;
    }
}

// ---------------- Output MLP: 64->64 elu (MFMA) ->32 elu (MFMA) ->8 (VALU),
// bf16 h input ----------------
__global__ __launch_bounds__(256) void mlp_kernel(const u16* __restrict__ h,
    const float* __restrict__ w1, const float* __restrict__ b1,
    const float* __restrict__ w2, const float* __restrict__ b2,
    const float* __restrict__ w3, const float* __restrict__ b3,
    float* __restrict__ out)
{
    __shared__ u16 hs[64 * 72];
    __shared__ u16 w1s[64 * 72];
    __shared__ u16 t1s[64 * 72];
    __shared__ u16 w2s[32 * 72];
    __shared__ float t2s[64 * 33];
    __shared__ float w3s[8 * 33];
    __shared__ float b1s[64], b2s[32], b3s[8];
    int t = threadIdx.x;
    int m0 = blockIdx.x * 64;

    #pragma unroll
    for (int it = 0; it < 2; ++it) {
        int p = t + it * 256; int row = p >> 3, kc = (p & 7) * 8;
        uint4 val = make_uint4(0u, 0u, 0u, 0u);
        if (m0 + row < N_NODES) val = *(const uint4*)(h + (size_t)(m0 + row) * 64 + kc);
        *(uint4*)&hs[row * 72 + kc] = val;
    }
    #pragma unroll
    for (int r = 0; r < 4; ++r) {
        int p = t + r * 256; int row = p >> 4, kc = (p & 15) * 4;
        float4 val = *(const float4*)(w1 + row * 64 + kc);
        ushort4 u; u.x = f2b(val.x); u.y = f2b(val.y); u.z = f2b(val.z); u.w = f2b(val.w);
        *(ushort4*)&w1s[row * 72 + kc] = u;
    }
    #pragma unroll
    for (int r = 0; r < 2; ++r) {
        int p = t + r * 256; int row = p >> 4, kc = (p & 15) * 4;
        float4 val = *(const float4*)(w2 + row * 64 + kc);
        ushort4 u; u.x = f2b(val.x); u.y = f2b(val.y); u.z = f2b(val.z); u.w = f2b(val.w);
        *(ushort4*)&w2s[row * 72 + kc] = u;
    }
    if (t < 8 * 32) { int r = t >> 5, c = t & 31; w3s[r * 33 + c] = w3[t]; }
    if (t < 64) b1s[t] = b1[t];
    if (t >= 64 && t < 96) b2s[t - 64] = b2[t - 64];
    if (t >= 96 && t < 104) b3s[t - 96] = b3[t - 96];
    __syncthreads();

    int wave = t >> 6, lane = t & 63;
    int lrow = lane & 15, quad = lane >> 4;
    int m_off = wave * 16;

    {
        bf16x8 a0 = *(const bf16x8*)&hs[(m_off + lrow) * 72 + quad * 8];
        bf16x8 a1 = *(const bf16x8*)&hs[(m_off + lrow) * 72 + 32 + quad * 8];
        #pragma unroll
        for (int nsub = 0; nsub < 4; ++nsub) {
            bf16x8 b0 = *(const bf16x8*)&w1s[(nsub * 16 + lrow) * 72 + quad * 8];
            bf16x8 b1v = *(const bf16x8*)&w1s[(nsub * 16 + lrow) * 72 + 32 + quad * 8];
            f32x4 acc = {0.f, 0.f, 0.f, 0.f};
            acc = __builtin_amdgcn_mfma_f32_16x16x32_bf16(a0, b0, acc, 0, 0, 0);
            acc = __builtin_amdgcn_mfma_f32_16x16x32_bf16(a1, b1v, acc, 0, 0, 0);
            int col = nsub * 16 + lrow;
            float bias = b1s[col];
            #pragma unroll
            for (int r = 0; r < 4; ++r) {
                int row = m_off + quad * 4 + r;
                t1s[row * 72 + col] = f2b(elu_f(acc[r] + bias));
            }
        }
    }
    __syncthreads();

    {
        bf16x8 a0 = *(const bf16x8*)&t1s[(m_off + lrow) * 72 + quad * 8];
        bf16x8 a1 = *(const bf16x8*)&t1s[(m_off + lrow) * 72 + 32 + quad * 8];
        #pragma unroll
        for (int nsub = 0; nsub < 2; ++nsub) {
            bf16x8 b0 = *(const bf16x8*)&w2s[(nsub * 16 + lrow) * 72 + quad * 8];
            bf16x8 b1v = *(const bf16x8*)&w2s[(nsub * 16 + lrow) * 72 + 32 + quad * 8];
            f32x4 acc = {0.f, 0.f, 0.f, 0.f};
            acc = __builtin_amdgcn_mfma_f32_16x16x32_bf16(a0, b0, acc, 0, 0, 0);
            acc = __builtin_amdgcn_mfma_f32_16x16x32_bf16(a1, b1v, acc, 0, 0, 0);
            int col = nsub * 16 + lrow;
            float bias = b2s[col];
            #pragma unroll
            for (int r = 0; r < 4; ++r) {
                int row = m_off + quad * 4 + r;
                t2s[row * 33 + col] = elu_f(acc[r] + bias);
            }
        }
    }
    __syncthreads();

    #pragma unroll
    for (int r = 0; r < 2; ++r) {
        int idx = t + r * 256;
        int node = idx >> 3, j = idx & 7;
        int row = m0 + node;
        if (row < N_NODES) {
            float acc = b3s[j];
            #pragma unroll
            for (int kk = 0; kk < 32; ++kk) acc += t2s[node * 33 + kk] * w3s[j * 33 + kk];
            out[(size_t)row * 8 + j] = acc;
        }
    }
}

extern "C" void kernel_launch(void* const* d_in, const int* in_sizes, int n_in,
                              void* d_out, int out_size, void* d_ws, size_t ws_size,
                              hipStream_t stream) {
    (void)in_sizes; (void)n_in; (void)out_size; (void)ws_size;
    const float* x   = (const float*)d_in[0];
    const int* ei    = (const int*)d_in[1];
    const float* ew1 = (const float*)d_in[2];
    const float* eb1 = (const float*)d_in[3];
    const float* ew2 = (const float*)d_in[4];
    const float* eb2 = (const float*)d_in[5];
    const float* Wq  = (const float*)d_in[6];
    const float* bq  = (const float*)d_in[7];
    const float* Wk  = (const float*)d_in[8];
    const float* bk  = (const float*)d_in[9];
    const float* Wv  = (const float*)d_in[10];
    const float* bv  = (const float*)d_in[11];
    const float* Wsk = (const float*)d_in[12];
    const float* bsk = (const float*)d_in[13];
    const float* ow1 = (const float*)d_in[14];
    const float* ob1 = (const float*)d_in[15];
    const float* ow2 = (const float*)d_in[16];
    const float* ob2 = (const float*)d_in[17];
    const float* ow3 = (const float*)d_in[18];
    const float* ob3 = (const float*)d_in[19];

    char* ws = (char*)d_ws;
    size_t off = 0;
    auto alloc = [&](size_t bytes) -> void* {
        void* p = ws + off;
        off += (bytes + 255) & ~(size_t)255;
        return p;
    };
    u16*   h0    = (u16*)  alloc((size_t)N_NODES * 64 * 2);
    u16*   h1    = (u16*)  alloc((size_t)N_NODES * 64 * 2);
    u16*   q     = (u16*)  alloc((size_t)N_NODES * 256 * 2);
    u8*    kv    = (u8*)   alloc((size_t)N_NODES * 512);
    float* skp   = (float*)alloc((size_t)N_NODES * 64 * 4);
    u16*   w16   = (u16*)  alloc((size_t)212992 * 2);
    int*   cnt   = (int*)  alloc((size_t)N_NODES * 4);   // cnt+cursor contiguous (each padded to 200192)
    int*   cursor= (int*)  alloc((size_t)N_NODES * 4);
    int*   rowst = (int*)  alloc((size_t)(N_NODES + 1) * 4);
    int*   csr   = (int*)  alloc((size_t)N_EDGES * 4);
    int*   bsum  = (int*)  alloc(512);
    int*   flag  = (int*)  alloc(256);

    u16* wq16  = w16;
    u16* wk16  = w16 + 65536;
    u16* wv16  = w16 + 131072;
    u16* wsk16 = w16 + 196608;

    const int NB = (N_NODES + 511) / 512;   // 98 scan blocks

    // zero cnt+cursor in one memset (adjacent 200192-byte padded allocations)
    hipMemsetAsync(cnt, 0, 2 * 200192, stream);
    detect_kernel<<<1, 256, 0, stream>>>(ei, flag);
    wcvt_kernel<<<208, 256, 0, stream>>>(Wq, Wk, Wv, Wsk, w16);
    hist_kernel<<<(N_EDGES + 255) / 256, 256, 0, stream>>>(ei, flag, cnt);
    scan1_kernel<<<NB, 512, 0, stream>>>(cnt, rowst, bsum);
    scan2_kernel<<<1, 128, 0, stream>>>(bsum, rowst);
    scan3_kernel<<<NB, 512, 0, stream>>>(rowst, bsum);
    scatter_kernel<<<(N_EDGES + 255) / 256, 256, 0, stream>>>(ei, flag, rowst, cursor, csr);

    encoder_kernel<<<(N_NODES + 63) / 64, 256, 0, stream>>>(x, ew1, eb1, ew2, eb2, h0);

    u16* hin = h0;
    u16* hout = h1;
    for (int l = 0; l < 4; ++l) {
        proj_kernel<<<(N_NODES + 63) / 64, 256, 0, stream>>>(hin, wq16, wk16, wv16, wsk16,
                                                             bq, bk, bv, bsk, l, q, kv, skp);
        attn_kernel<<<(N_NODES + 3) / 4, 256, 0, stream>>>(q, kv, skp, rowst, csr, hout);
        u16* tmp = hin; hin = hout; hout = tmp;
    }

    mlp_kernel<<<(N_NODES + 63) / 64, 256, 0, stream>>>(hin, ow1, ob1, ow2, ob2, ow3, ob3, (float*)d_out);
}

// Round 6
// 441.712 us; speedup vs baseline: 1.5776x; 1.0325x over previous
//
#include <hip/hip_runtime.h>
#include <hip/hip_bf16.h>

#define N_NODES 50000
#define N_EDGES 500000
constexpr int HID = 64;
constexpr int HC  = 256;   // HEADS*HID

typedef unsigned short u16;
typedef unsigned char u8;
typedef __attribute__((ext_vector_type(8))) __bf16 bf16x8;
typedef __attribute__((ext_vector_type(4))) float f32x4;
typedef __attribute__((ext_vector_type(2))) float f32x2;

__device__ __forceinline__ float b2f(u16 u) {
    union { unsigned int i; float f; } c; c.i = ((unsigned int)u) << 16; return c.f;
}
__device__ __forceinline__ u16 f2b(float f) {
    union { float f; unsigned int i; } c; c.f = f;
    unsigned int x = c.i;
    unsigned int lsb = (x >> 16) & 1u;
    x += 0x7fffu + lsb;
    return (u16)(x >> 16);
}
__device__ __forceinline__ float elu_f(float x) { return x > 0.f ? x : expm1f(x); }

// h is stored bf16 (u16) everywhere (bit-identical downstream).
// kv fp8 layout (scale 16, e4m3): group g (8B) = [k ch 4g..4g+3][v ch 4g..4g+3]

// ---------------- edge_index layout detect (int32 vs int64) ----------------
__global__ __launch_bounds__(256) void detect_kernel(const int* __restrict__ ei, int* __restrict__ flag) {
    __shared__ int s[4];
    int t = threadIdx.x;
    int nz = ei[2 * t + 1] != 0;
    unsigned long long m = __ballot(nz);
    if ((t & 63) == 0) s[t >> 6] = (m != 0ull) ? 1 : 0;
    __syncthreads();
    if (t == 0) flag[0] = s[0] | s[1] | s[2] | s[3];   // 1 => int32 layout
}

// ---------------- weight pre-conversion fp32 -> bf16 (once) ----------------
__global__ __launch_bounds__(256) void wcvt_kernel(const float* __restrict__ Wq, const float* __restrict__ Wk,
                                                   const float* __restrict__ Wv, const float* __restrict__ Wsk,
                                                   u16* __restrict__ w16) {
    int i = blockIdx.x * 256 + threadIdx.x;   // float4 index
    if (i >= 53248) return;
    const float* src; int off;
    if (i < 16384)      { src = Wq;  off = i; }
    else if (i < 32768) { src = Wk;  off = i - 16384; }
    else if (i < 49152) { src = Wv;  off = i - 32768; }
    else                { src = Wsk; off = i - 49152; }
    float4 v = ((const float4*)src)[off];
    ushort4 u; u.x = f2b(v.x); u.y = f2b(v.y); u.z = f2b(v.z); u.w = f2b(v.w);
    ((ushort4*)w16)[i] = u;
}

// ---------------- CSR build (counting sort by dst) ----------------
__global__ __launch_bounds__(256) void hist_kernel(const int* __restrict__ ei, const int* __restrict__ flag,
                                                   int* __restrict__ cnt) {
    int e = blockIdx.x * 256 + threadIdx.x;
    if (e < N_EDGES) {
        int d = flag[0] ? ei[N_EDGES + e] : ei[2 * N_EDGES + 2 * e];
        atomicAdd(&cnt[d], 1);
    }
}

__global__ __launch_bounds__(512) void scan1_kernel(const int* __restrict__ cnt,
                                                    int* __restrict__ row_start, int* __restrict__ bsum) {
    __shared__ int sc[512];
    int t = threadIdx.x;
    int i = blockIdx.x * 512 + t;
    int v = (i < N_NODES) ? cnt[i] : 0;
    sc[t] = v;
    __syncthreads();
    for (int off = 1; off < 512; off <<= 1) {
        int u = (t >= off) ? sc[t - off] : 0;
        __syncthreads();
        sc[t] += u;
        __syncthreads();
    }
    if (i < N_NODES) row_start[i] = sc[t] - v;
    if (t == 511) bsum[blockIdx.x] = sc[511];
}

__global__ __launch_bounds__(128) void scan2_kernel(int* __restrict__ bsum, int* __restrict__ row_start) {
    __shared__ int sc[128];
    const int NB = (N_NODES + 511) / 512;  // 98
    int t = threadIdx.x;
    int v = (t < NB) ? bsum[t] : 0;
    sc[t] = v;
    __syncthreads();
    for (int off = 1; off < 128; off <<= 1) {
        int u = (t >= off) ? sc[t - off] : 0;
        __syncthreads();
        sc[t] += u;
        __syncthreads();
    }
    if (t < NB) bsum[t] = sc[t] - v;
    if (t == 127) row_start[N_NODES] = sc[127];
}

__global__ __launch_bounds__(512) void scan3_kernel(int* __restrict__ row_start, const int* __restrict__ bsum) {
    int i = blockIdx.x * 512 + threadIdx.x;
    if (i < N_NODES) row_start[i] += bsum[blockIdx.x];
}

__global__ __launch_bounds__(256) void scatter_kernel(const int* __restrict__ ei, const int* __restrict__ flag,
                                const int* __restrict__ row_start, int* __restrict__ cursor,
                                int* __restrict__ csr_src) {
    int e = blockIdx.x * 256 + threadIdx.x;
    if (e < N_EDGES) {
        int isI32 = flag[0];
        int s = isI32 ? ei[e] : ei[2 * e];
        int d = isI32 ? ei[N_EDGES + e] : ei[2 * N_EDGES + 2 * e];
        int pos = row_start[d] + atomicAdd(&cursor[d], 1);
        csr_src[pos] = s;
    }
}

// ---------------- Encoder: 8->64 elu (VALU) -> 64->64 elu (MFMA), bf16 out ----------------
__global__ __launch_bounds__(256) void encoder_kernel(const float* __restrict__ x,
                               const float* __restrict__ w1, const float* __restrict__ b1,
                               const float* __restrict__ w2, const float* __restrict__ b2,
                               u16* __restrict__ h) {
    __shared__ float xs[64 * 9];
    __shared__ float w1s[64 * 9];
    __shared__ u16 t1s[64 * 72];
    __shared__ u16 w2s[64 * 72];
    __shared__ float b1s[64], b2s[64];
    int t = threadIdx.x;
    int m0 = blockIdx.x * 64;

    if (t < 128) {
        int row = t >> 1, c = (t & 1) * 4;
        float4 val = make_float4(0.f, 0.f, 0.f, 0.f);
        if (m0 + row < N_NODES) val = *(const float4*)(x + (size_t)(m0 + row) * 8 + c);
        *(float4*)&xs[row * 9 + c] = val;
    }
    if (t >= 128 && t < 256) {
        int p = t - 128;
        int row = p >> 1, c = (p & 1) * 4;
        float4 val = *(const float4*)(w1 + row * 8 + c);
        *(float4*)&w1s[row * 9 + c] = val;
    }
    #pragma unroll
    for (int r = 0; r < 4; ++r) {
        int p = t + r * 256; int row = p >> 4, kc = (p & 15) * 4;
        float4 val = *(const float4*)(w2 + row * 64 + kc);
        ushort4 u; u.x = f2b(val.x); u.y = f2b(val.y); u.z = f2b(val.z); u.w = f2b(val.w);
        *(ushort4*)&w2s[row * 72 + kc] = u;
    }
    if (t < 64) { b1s[t] = b1[t]; b2s[t] = b2[t]; }
    __syncthreads();

    {
        int j = t & 63, sub = t >> 6;
        #pragma unroll
        for (int g = 0; g < 16; ++g) {
            int node = g * 4 + sub;
            float acc = b1s[j];
            #pragma unroll
            for (int m = 0; m < 8; ++m) acc += xs[node * 9 + m] * w1s[j * 9 + m];
            t1s[node * 72 + j] = f2b(elu_f(acc));
        }
    }
    __syncthreads();

    int wave = t >> 6, lane = t & 63;
    int lrow = lane & 15, quad = lane >> 4;
    int m_off = wave * 16;
    bf16x8 a0 = *(const bf16x8*)&t1s[(m_off + lrow) * 72 + quad * 8];
    bf16x8 a1 = *(const bf16x8*)&t1s[(m_off + lrow) * 72 + 32 + quad * 8];
    #pragma unroll
    for (int nsub = 0; nsub < 4; ++nsub) {
        bf16x8 b0 = *(const bf16x8*)&w2s[(nsub * 16 + lrow) * 72 + quad * 8];
        bf16x8 b1v = *(const bf16x8*)&w2s[(nsub * 16 + lrow) * 72 + 32 + quad * 8];
        f32x4 acc = {0.f, 0.f, 0.f, 0.f};
        acc = __builtin_amdgcn_mfma_f32_16x16x32_bf16(a0, b0, acc, 0, 0, 0);
        acc = __builtin_amdgcn_mfma_f32_16x16x32_bf16(a1, b1v, acc, 0, 0, 0);
        int col = nsub * 16 + lrow;
        float bias = b2s[col];
        #pragma unroll
        for (int r = 0; r < 4; ++r) {
            int row = m0 + m_off + quad * 4 + r;
            if (row < N_NODES) h[(size_t)row * 64 + col] = f2b(elu_f(acc[r] + bias));
        }
    }
}

// ---------------- Projection v4: 128 nodes/block (each lane owns two node
// fragments), double-buffered weight staging. Halves block count, per-node
// barrier cost, and weight L2 re-reads vs v3. Same math per node. ----------------
__global__ __launch_bounds__(256) void proj_kernel(const u16* __restrict__ h,
    const u16* __restrict__ wq16, const u16* __restrict__ wk16,
    const u16* __restrict__ wv16, const u16* __restrict__ wsk16,
    const float* __restrict__ bq, const float* __restrict__ bk,
    const float* __restrict__ bv, const float* __restrict__ bsk,
    int layer,
    u16* __restrict__ q, u8* __restrict__ kv, float* __restrict__ skip)
{
    __shared__ u16 wsA[64 * 72];         // double-buffered weight tile / h stage lo
    __shared__ u16 wsB[64 * 72];         // double-buffered weight tile / h stage hi
    __shared__ float pool[128 * 68];     // 34816 B: qst u16[128*72] / kvst u8[128*144] / skst f32[128*68]
    u16* qst  = (u16*)pool;
    u8*  kvst = (u8*)pool;
    float* skst = pool;

    int t = threadIdx.x;
    int m0 = blockIdx.x * 128;
    int wave = t >> 6, lane = t & 63;
    int lrow = lane & 15, quad = lane >> 4;
    int nl0 = wave * 16 + lrow;          // node set 0: 0..63
    int nl1 = 64 + nl0;                  // node set 1: 64..127

    const u16* Wq16  = wq16  + (size_t)layer * HC * HID;
    const u16* Wk16  = wk16  + (size_t)layer * HC * HID;
    const u16* Wv16  = wv16  + (size_t)layer * HC * HID;
    const u16* Wsk16 = wsk16 + (size_t)layer * HID * HID;
    const float* bqL  = bq  + layer * HC;
    const float* bkL  = bk  + layer * HC;
    const float* bvL  = bv  + layer * HC;
    const float* bskL = bsk + layer * HID;

    auto stageIssue = [&](const u16* W, int cb, uint4& r0, uint4& r1) {
        const u16* sp = W + (size_t)(cb + (t >> 3)) * 64 + (t & 7) * 8;
        r0 = *(const uint4*)sp;
        r1 = *(const uint4*)(sp + 2048);    // +32 rows
    };
    auto stageWrite = [&](u16* buf, uint4 r0, uint4 r1) {
        int row = t >> 3, kc = (t & 7) * 8;
        *(uint4*)&buf[row * 72 + kc] = r0;
        *(uint4*)&buf[(row + 32) * 72 + kc] = r1;
    };

    // ---- prologue: issue h (16KB) + Q0 weight loads, then stage ----
    uint4 hv[4];
    #pragma unroll
    for (int it = 0; it < 4; ++it) {
        int p = t + it * 256; int row = p >> 3, kc = (p & 7) * 8;
        hv[it] = make_uint4(0u, 0u, 0u, 0u);
        if (m0 + row < N_NODES) hv[it] = *(const uint4*)(h + (size_t)(m0 + row) * 64 + kc);
    }
    uint4 q0r0, q0r1;
    stageIssue(Wq16, 0, q0r0, q0r1);
    #pragma unroll
    for (int it = 0; it < 4; ++it) {
        int p = t + it * 256; int row = p >> 3, kc = (p & 7) * 8;
        if (row < 64) *(uint4*)&wsA[row * 72 + kc] = hv[it];
        else          *(uint4*)&wsB[(row - 64) * 72 + kc] = hv[it];
    }
    __syncthreads();
    bf16x8 a0 = *(const bf16x8*)&wsA[nl0 * 72 + quad * 8];
    bf16x8 a1 = *(const bf16x8*)&wsA[nl0 * 72 + 32 + quad * 8];
    bf16x8 a2 = *(const bf16x8*)&wsB[nl0 * 72 + quad * 8];
    bf16x8 a3 = *(const bf16x8*)&wsB[nl0 * 72 + 32 + quad * 8];
    __syncthreads();
    stageWrite(wsB, q0r0, q0r1);
    __syncthreads();

    auto computeQ = [&](int ct, const u16* BUF) {
        #pragma unroll
        for (int nsub = 0; nsub < 4; ++nsub) {
            bf16x8 w0 = *(const bf16x8*)&BUF[(nsub * 16 + lrow) * 72 + quad * 8];
            bf16x8 w1 = *(const bf16x8*)&BUF[(nsub * 16 + lrow) * 72 + 32 + quad * 8];
            float4 b4 = *(const float4*)(bqL + ct * 64 + nsub * 16 + quad * 4);
            f32x4 acc = {0.f, 0.f, 0.f, 0.f};
            acc = __builtin_amdgcn_mfma_f32_16x16x32_bf16(w0, a0, acc, 0, 0, 0);
            acc = __builtin_amdgcn_mfma_f32_16x16x32_bf16(w1, a1, acc, 0, 0, 0);
            ushort4 o;
            o.x = f2b(acc[0] + b4.x); o.y = f2b(acc[1] + b4.y);
            o.z = f2b(acc[2] + b4.z); o.w = f2b(acc[3] + b4.w);
            *(ushort4*)&qst[nl0 * 72 + nsub * 16 + quad * 4] = o;
            f32x4 acc2 = {0.f, 0.f, 0.f, 0.f};
            acc2 = __builtin_amdgcn_mfma_f32_16x16x32_bf16(w0, a2, acc2, 0, 0, 0);
            acc2 = __builtin_amdgcn_mfma_f32_16x16x32_bf16(w1, a3, acc2, 0, 0, 0);
            ushort4 o2;
            o2.x = f2b(acc2[0] + b4.x); o2.y = f2b(acc2[1] + b4.y);
            o2.z = f2b(acc2[2] + b4.z); o2.w = f2b(acc2[3] + b4.w);
            *(ushort4*)&qst[nl1 * 72 + nsub * 16 + quad * 4] = o2;
        }
    };
    auto computeKV = [&](int ct, const u16* BUF, const float* bias, int voff) {
        #pragma unroll
        for (int nsub = 0; nsub < 4; ++nsub) {
            bf16x8 w0 = *(const bf16x8*)&BUF[(nsub * 16 + lrow) * 72 + quad * 8];
            bf16x8 w1 = *(const bf16x8*)&BUF[(nsub * 16 + lrow) * 72 + 32 + quad * 8];
            float4 b4 = *(const float4*)(bias + ct * 64 + nsub * 16 + quad * 4);
            int g = nsub * 4 + quad;
            f32x4 acc = {0.f, 0.f, 0.f, 0.f};
            acc = __builtin_amdgcn_mfma_f32_16x16x32_bf16(w0, a0, acc, 0, 0, 0);
            acc = __builtin_amdgcn_mfma_f32_16x16x32_bf16(w1, a1, acc, 0, 0, 0);
            {
                float f0 = (acc[0] + b4.x) * 16.f, f1 = (acc[1] + b4.y) * 16.f;
                float f2v = (acc[2] + b4.z) * 16.f, f3v = (acc[3] + b4.w) * 16.f;
                int pk = __builtin_amdgcn_cvt_pk_fp8_f32(f0, f1, 0, false);
                pk = __builtin_amdgcn_cvt_pk_fp8_f32(f2v, f3v, pk, true);
                *(unsigned int*)&kvst[nl0 * 144 + g * 8 + voff] = (unsigned int)pk;
            }
            f32x4 acc2 = {0.f, 0.f, 0.f, 0.f};
            acc2 = __builtin_amdgcn_mfma_f32_16x16x32_bf16(w0, a2, acc2, 0, 0, 0);
            acc2 = __builtin_amdgcn_mfma_f32_16x16x32_bf16(w1, a3, acc2, 0, 0, 0);
            {
                float f0 = (acc2[0] + b4.x) * 16.f, f1 = (acc2[1] + b4.y) * 16.f;
                float f2v = (acc2[2] + b4.z) * 16.f, f3v = (acc2[3] + b4.w) * 16.f;
                int pk = __builtin_amdgcn_cvt_pk_fp8_f32(f0, f1, 0, false);
                pk = __builtin_amdgcn_cvt_pk_fp8_f32(f2v, f3v, pk, true);
                *(unsigned int*)&kvst[nl1 * 144 + g * 8 + voff] = (unsigned int)pk;
            }
        }
    };
    auto computeSK = [&](const u16* BUF) {
        #pragma unroll
        for (int nsub = 0; nsub < 4; ++nsub) {
            bf16x8 w0 = *(const bf16x8*)&BUF[(nsub * 16 + lrow) * 72 + quad * 8];
            bf16x8 w1 = *(const bf16x8*)&BUF[(nsub * 16 + lrow) * 72 + 32 + quad * 8];
            float4 b4 = *(const float4*)(bskL + nsub * 16 + quad * 4);
            f32x4 acc = {0.f, 0.f, 0.f, 0.f};
            acc = __builtin_amdgcn_mfma_f32_16x16x32_bf16(w0, a0, acc, 0, 0, 0);
            acc = __builtin_amdgcn_mfma_f32_16x16x32_bf16(w1, a1, acc, 0, 0, 0);
            float4 o;
            o.x = acc[0] + b4.x; o.y = acc[1] + b4.y;
            o.z = acc[2] + b4.z; o.w = acc[3] + b4.w;
            *(float4*)&skst[nl0 * 68 + nsub * 16 + quad * 4] = o;
            f32x4 acc2 = {0.f, 0.f, 0.f, 0.f};
            acc2 = __builtin_amdgcn_mfma_f32_16x16x32_bf16(w0, a2, acc2, 0, 0, 0);
            acc2 = __builtin_amdgcn_mfma_f32_16x16x32_bf16(w1, a3, acc2, 0, 0, 0);
            float4 o2;
            o2.x = acc2[0] + b4.x; o2.y = acc2[1] + b4.y;
            o2.z = acc2[2] + b4.z; o2.w = acc2[3] + b4.w;
            *(float4*)&skst[nl1 * 68 + nsub * 16 + quad * 4] = o2;
        }
    };
    auto flushQ = [&](int ct) {
        #pragma unroll
        for (int it = 0; it < 4; ++it) {
            int p = t + it * 256; int row = p >> 3, ch = p & 7;
            int grow = m0 + row;
            if (grow < N_NODES)
                *(uint4*)(q + (size_t)grow * 256 + ct * 64 + ch * 8) = *(const uint4*)&qst[row * 72 + ch * 8];
        }
    };
    auto flushKV = [&](int ct) {
        #pragma unroll
        for (int it = 0; it < 4; ++it) {
            int p = t + it * 256; int row = p >> 3, ch = p & 7;
            int grow = m0 + row;
            if (grow < N_NODES)
                *(uint4*)(kv + (size_t)grow * 512 + ct * 128 + ch * 16) = *(const uint4*)&kvst[row * 144 + ch * 16];
        }
    };

    uint4 r0, r1;
    // tiles: Q0(B) Q1(A) Q2(B) Q3(A) K0(B) V0(A) K1(B) V1(A) K2(B) V2(A) K3(B) V3(A) SK(B)
    stageIssue(Wq16, 64, r0, r1);  computeQ(0, wsB);          __syncthreads(); flushQ(0);  stageWrite(wsA, r0, r1); __syncthreads();
    stageIssue(Wq16, 128, r0, r1); computeQ(1, wsA);          __syncthreads(); flushQ(1);  stageWrite(wsB, r0, r1); __syncthreads();
    stageIssue(Wq16, 192, r0, r1); computeQ(2, wsB);          __syncthreads(); flushQ(2);  stageWrite(wsA, r0, r1); __syncthreads();
    stageIssue(Wk16, 0, r0, r1);   computeQ(3, wsA);          __syncthreads(); flushQ(3);  stageWrite(wsB, r0, r1); __syncthreads();
    stageIssue(Wv16, 0, r0, r1);   computeKV(0, wsB, bkL, 0); __syncthreads();             stageWrite(wsA, r0, r1); __syncthreads();
    stageIssue(Wk16, 64, r0, r1);  computeKV(0, wsA, bvL, 4); __syncthreads(); flushKV(0); stageWrite(wsB, r0, r1); __syncthreads();
    stageIssue(Wv16, 64, r0, r1);  computeKV(1, wsB, bkL, 0); __syncthreads();             stageWrite(wsA, r0, r1); __syncthreads();
    stageIssue(Wk16, 128, r0, r1); computeKV(1, wsA, bvL, 4); __syncthreads(); flushKV(1); stageWrite(wsB, r0, r1); __syncthreads();
    stageIssue(Wv16, 128, r0, r1); computeKV(2, wsB, bkL, 0); __syncthreads();             stageWrite(wsA, r0, r1); __syncthreads();
    stageIssue(Wk16, 192, r0, r1); computeKV(2, wsA, bvL, 4); __syncthreads(); flushKV(2); stageWrite(wsB, r0, r1); __syncthreads();
    stageIssue(Wv16, 192, r0, r1); computeKV(3, wsB, bkL, 0); __syncthreads();             stageWrite(wsA, r0, r1); __syncthreads();
    stageIssue(Wsk16, 0, r0, r1);  computeKV(3, wsA, bvL, 4); __syncthreads(); flushKV(3); stageWrite(wsB, r0, r1); __syncthreads();

    // ---- last phase: skip tile (fp32 out) ----
    computeSK(wsB);
    __syncthreads();
    #pragma unroll
    for (int it = 0; it < 2; ++it) {
        int p = t + it * 256; int row = p >> 2, c0 = (p & 3) * 16;
        int grow = m0 + row;
        if (grow < N_NODES) {
            #pragma unroll
            for (int j = 0; j < 4; ++j)
                *(float4*)(skip + (size_t)grow * 64 + c0 + j * 4) = *(const float4*)&skst[row * 68 + c0 + j * 4];
        }
    }
}

// ---------------- Attention v5: v3 structure + DPP 16-lane butterfly.
// After xor1+xor2 each quad holds its quad-sum, so row_half_mirror / row_mirror
// deliver exactly the lane^4 / lane^8 values -> bitwise identical to shfl_xor. ----------------
#define DPP_ADD(x, ctrl) ((x) + __builtin_bit_cast(float, \
    __builtin_amdgcn_update_dpp(0, __builtin_bit_cast(int, (x)), (ctrl), 0xf, 0xf, true)))

#define ATTN_QUAD(S0q, S1q, S2q, S3q, V1, V2, V3) do { \
    uint2 c0 = *(const uint2*)(kvl + (size_t)(unsigned)(S0q) * 512); \
    uint2 c1 = *(const uint2*)(kvl + (size_t)(unsigned)(S1q) * 512); \
    uint2 c2 = *(const uint2*)(kvl + (size_t)(unsigned)(S2q) * 512); \
    uint2 c3 = *(const uint2*)(kvl + (size_t)(unsigned)(S3q) * 512); \
    f32x2 k0a = __builtin_amdgcn_cvt_pk_f32_fp8(c0.x, false), k0b = __builtin_amdgcn_cvt_pk_f32_fp8(c0.x, true); \
    f32x2 k1a = __builtin_amdgcn_cvt_pk_f32_fp8(c1.x, false), k1b = __builtin_amdgcn_cvt_pk_f32_fp8(c1.x, true); \
    f32x2 k2a = __builtin_amdgcn_cvt_pk_f32_fp8(c2.x, false), k2b = __builtin_amdgcn_cvt_pk_f32_fp8(c2.x, true); \
    f32x2 k3a = __builtin_amdgcn_cvt_pk_f32_fp8(c3.x, false), k3b = __builtin_amdgcn_cvt_pk_f32_fp8(c3.x, true); \
    f32x2 pd0 = qlo * k0a + qhi * k0b; \
    f32x2 pd1 = qlo * k1a + qhi * k1b; \
    f32x2 pd2 = qlo * k2a + qhi * k2b; \
    f32x2 pd3 = qlo * k3a + qhi * k3b; \
    float p0 = pd0.x + pd0.y, p1 = pd1.x + pd1.y, p2 = pd2.x + pd2.y, p3 = pd3.x + pd3.y; \
    p0 = DPP_ADD(p0, 0xB1);  p1 = DPP_ADD(p1, 0xB1);  p2 = DPP_ADD(p2, 0xB1);  p3 = DPP_ADD(p3, 0xB1);  \
    p0 = DPP_ADD(p0, 0x4E);  p1 = DPP_ADD(p1, 0x4E);  p2 = DPP_ADD(p2, 0x4E);  p3 = DPP_ADD(p3, 0x4E);  \
    p0 = DPP_ADD(p0, 0x141); p1 = DPP_ADD(p1, 0x141); p2 = DPP_ADD(p2, 0x141); p3 = DPP_ADD(p3, 0x141); \
    p0 = DPP_ADD(p0, 0x140); p1 = DPP_ADD(p1, 0x140); p2 = DPP_ADD(p2, 0x140); p3 = DPP_ADD(p3, 0x140); \
    float w0 = __expf(p0 * SC); \
    float w1 = (V1) ? __expf(p1 * SC) : 0.f; \
    float w2 = (V2) ? __expf(p2 * SC) : 0.f; \
    float w3 = (V3) ? __expf(p3 * SC) : 0.f; \
    l += (w0 + w1) + (w2 + w3); \
    f32x2 v0a = __builtin_amdgcn_cvt_pk_f32_fp8(c0.y, false), v0b = __builtin_amdgcn_cvt_pk_f32_fp8(c0.y, true); \
    f32x2 v1a = __builtin_amdgcn_cvt_pk_f32_fp8(c1.y, false), v1b = __builtin_amdgcn_cvt_pk_f32_fp8(c1.y, true); \
    f32x2 v2a = __builtin_amdgcn_cvt_pk_f32_fp8(c2.y, false), v2b = __builtin_amdgcn_cvt_pk_f32_fp8(c2.y, true); \
    f32x2 v3a = __builtin_amdgcn_cvt_pk_f32_fp8(c3.y, false), v3b = __builtin_amdgcn_cvt_pk_f32_fp8(c3.y, true); \
    accA += v0a * w0; accA += v1a * w1; accA += v2a * w2; accA += v3a * w3; \
    accB += v0b * w0; accB += v1b * w1; accB += v2b * w2; accB += v3b * w3; \
} while (0)

__global__ __launch_bounds__(256) void attn_kernel(
    const u16* __restrict__ q, const u8* __restrict__ kv,
    const float* __restrict__ skip,
    const int* __restrict__ row_start, const int* __restrict__ csr_src,
    u16* __restrict__ hout)
{
    __shared__ int s_lds[4][64];     // per-wave private row: no barrier needed
    int wave = threadIdx.x >> 6;
    int lane = threadIdx.x & 63;
    int n = blockIdx.x * 4 + wave;
    if (n >= N_NODES) return;
    ushort4 q4 = ((const ushort4*)(q + (size_t)n * 256))[lane];
    f32x2 qlo = { b2f(q4.x), b2f(q4.y) };
    f32x2 qhi = { b2f(q4.z), b2f(q4.w) };
    const u8* kvl = kv + lane * 8;
    const float SC = 0.0078125f;   // 1/(8*16)
    float l = 0.f;
    f32x2 accA = {0.f, 0.f};
    f32x2 accB = {0.f, 0.f};
    int e0 = row_start[n];
    int deg = row_start[n + 1] - e0;

    for (int base = 0; base < deg; base += 64) {
        int rem = deg - base;
        int m = rem < 64 ? rem : 64;
        int li = lane < m ? lane : m - 1;           // clamp: stay inside this row's edges
        s_lds[wave][lane] = csr_src[e0 + base + li]; // one coalesced load per 64 edges
        int i = 0;
        for (; i + 4 <= m; i += 4) {
            int4 sq = *(const int4*)&s_lds[wave][i];  // uniform addr -> LDS broadcast
            ATTN_QUAD(sq.x, sq.y, sq.z, sq.w, 1, 1, 1);
        }
        if (i < m) {                                  // tail: 1..3 edges, masked quad
            int4 sq = *(const int4*)&s_lds[wave][i];  // i%4==0, i<=60: aligned, in-bounds
            int rem2 = m - i;
            int sB = rem2 > 1 ? sq.y : sq.x;
            int sC = rem2 > 2 ? sq.z : sq.x;
            ATTN_QUAD(sq.x, sB, sC, sq.x, rem2 > 1, rem2 > 2, 0);
        }
    }

    float inv = l > 0.f ? 1.f / l : 0.f;
    float a0 = accA.x * inv, a1 = accA.y * inv;
    float a2 = accB.x * inv, a3 = accB.y * inv;
    a0 += __shfl_xor(a0, 16); a0 += __shfl_xor(a0, 32);
    a1 += __shfl_xor(a1, 16); a1 += __shfl_xor(a1, 32);
    a2 += __shfl_xor(a2, 16); a2 += __shfl_xor(a2, 32);
    a3 += __shfl_xor(a3, 16); a3 += __shfl_xor(a3, 32);
    if ((lane >> 4) == 0) {
        const float OS = 0.015625f;  // 0.25 (head mean) * 1/16 (v scale)
        float4 sk = ((const float4*)(skip + (size_t)n * 64))[lane];
        ushort4 o;
        o.x = f2b(elu_f(OS * a0 + sk.x));
        o.y = f2b(elu_f(OS * a1 + sk.y));
        o.z = f2b(elu_f(OS * a2 + sk.z));
        o.w = f2b(elu_f(OS * a3 + sk.w));
        ((ushort4*)(hout + (size_t)n * 64))[lane] = o;
    }
}

// ---------------- Output MLP: 64->64 elu (MFMA) ->32 elu (MFMA) ->8 (VALU),
// bf16 h input ----------------
__global__ __launch_bounds__(256) void mlp_kernel(const u16* __restrict__ h,
    const float* __restrict__ w1, const float* __restrict__ b1,
    const float* __restrict__ w2, const float* __restrict__ b2,
    const float* __restrict__ w3, const float* __restrict__ b3,
    float* __restrict__ out)
{
    __shared__ u16 hs[64 * 72];
    __shared__ u16 w1s[64 * 72];
    __shared__ u16 t1s[64 * 72];
    __shared__ u16 w2s[32 * 72];
    __shared__ float t2s[64 * 33];
    __shared__ float w3s[8 * 33];
    __shared__ float b1s[64], b2s[32], b3s[8];
    int t = threadIdx.x;
    int m0 = blockIdx.x * 64;

    #pragma unroll
    for (int it = 0; it < 2; ++it) {
        int p = t + it * 256; int row = p >> 3, kc = (p & 7) * 8;
        uint4 val = make_uint4(0u, 0u, 0u, 0u);
        if (m0 + row < N_NODES) val = *(const uint4*)(h + (size_t)(m0 + row) * 64 + kc);
        *(uint4*)&hs[row * 72 + kc] = val;
    }
    #pragma unroll
    for (int r = 0; r < 4; ++r) {
        int p = t + r * 256; int row = p >> 4, kc = (p & 15) * 4;
        float4 val = *(const float4*)(w1 + row * 64 + kc);
        ushort4 u; u.x = f2b(val.x); u.y = f2b(val.y); u.z = f2b(val.z); u.w = f2b(val.w);
        *(ushort4*)&w1s[row * 72 + kc] = u;
    }
    #pragma unroll
    for (int r = 0; r < 2; ++r) {
        int p = t + r * 256; int row = p >> 4, kc = (p & 15) * 4;
        float4 val = *(const float4*)(w2 + row * 64 + kc);
        ushort4 u; u.x = f2b(val.x); u.y = f2b(val.y); u.z = f2b(val.z); u.w = f2b(val.w);
        *(ushort4*)&w2s[row * 72 + kc] = u;
    }
    if (t < 8 * 32) { int r = t >> 5, c = t & 31; w3s[r * 33 + c] = w3[t]; }
    if (t < 64) b1s[t] = b1[t];
    if (t >= 64 && t < 96) b2s[t - 64] = b2[t - 64];
    if (t >= 96 && t < 104) b3s[t - 96] = b3[t - 96];
    __syncthreads();

    int wave = t >> 6, lane = t & 63;
    int lrow = lane & 15, quad = lane >> 4;
    int m_off = wave * 16;

    {
        bf16x8 a0 = *(const bf16x8*)&hs[(m_off + lrow) * 72 + quad * 8];
        bf16x8 a1 = *(const bf16x8*)&hs[(m_off + lrow) * 72 + 32 + quad * 8];
        #pragma unroll
        for (int nsub = 0; nsub < 4; ++nsub) {
            bf16x8 b0 = *(const bf16x8*)&w1s[(nsub * 16 + lrow) * 72 + quad * 8];
            bf16x8 b1v = *(const bf16x8*)&w1s[(nsub * 16 + lrow) * 72 + 32 + quad * 8];
            f32x4 acc = {0.f, 0.f, 0.f, 0.f};
            acc = __builtin_amdgcn_mfma_f32_16x16x32_bf16(a0, b0, acc, 0, 0, 0);
            acc = __builtin_amdgcn_mfma_f32_16x16x32_bf16(a1, b1v, acc, 0, 0, 0);
            int col = nsub * 16 + lrow;
            float bias = b1s[col];
            #pragma unroll
            for (int r = 0; r < 4; ++r) {
                int row = m_off + quad * 4 + r;
                t1s[row * 72 + col] = f2b(elu_f(acc[r] + bias));
            }
        }
    }
    __syncthreads();

    {
        bf16x8 a0 = *(const bf16x8*)&t1s[(m_off + lrow) * 72 + quad * 8];
        bf16x8 a1 = *(const bf16x8*)&t1s[(m_off + lrow) * 72 + 32 + quad * 8];
        #pragma unroll
        for (int nsub = 0; nsub < 2; ++nsub) {
            bf16x8 b0 = *(const bf16x8*)&w2s[(nsub * 16 + lrow) * 72 + quad * 8];
            bf16x8 b1v = *(const bf16x8*)&w2s[(nsub * 16 + lrow) * 72 + 32 + quad * 8];
            f32x4 acc = {0.f, 0.f, 0.f, 0.f};
            acc = __builtin_amdgcn_mfma_f32_16x16x32_bf16(a0, b0, acc, 0, 0, 0);
            acc = __builtin_amdgcn_mfma_f32_16x16x32_bf16(a1, b1v, acc, 0, 0, 0);
            int col = nsub * 16 + lrow;
            float bias = b2s[col];
            #pragma unroll
            for (int r = 0; r < 4; ++r) {
                int row = m_off + quad * 4 + r;
                t2s[row * 33 + col] = elu_f(acc[r] + bias);
            }
        }
    }
    __syncthreads();

    #pragma unroll
    for (int r = 0; r < 2; ++r) {
        int idx = t + r * 256;
        int node = idx >> 3, j = idx & 7;
        int row = m0 + node;
        if (row < N_NODES) {
            float acc = b3s[j];
            #pragma unroll
            for (int kk = 0; kk < 32; ++kk) acc += t2s[node * 33 + kk] * w3s[j * 33 + kk];
            out[(size_t)row * 8 + j] = acc;
        }
    }
}

extern "C" void kernel_launch(void* const* d_in, const int* in_sizes, int n_in,
                              void* d_out, int out_size, void* d_ws, size_t ws_size,
                              hipStream_t stream) {
    (void)in_sizes; (void)n_in; (void)out_size; (void)ws_size;
    const float* x   = (const float*)d_in[0];
    const int* ei    = (const int*)d_in[1];
    const float* ew1 = (const float*)d_in[2];
    const float* eb1 = (const float*)d_in[3];
    const float* ew2 = (const float*)d_in[4];
    const float* eb2 = (const float*)d_in[5];
    const float* Wq  = (const float*)d_in[6];
    const float* bq  = (const float*)d_in[7];
    const float* Wk  = (const float*)d_in[8];
    const float* bk  = (const float*)d_in[9];
    const float* Wv  = (const float*)d_in[10];
    const float* bv  = (const float*)d_in[11];
    const float* Wsk = (const float*)d_in[12];
    const float* bsk = (const float*)d_in[13];
    const float* ow1 = (const float*)d_in[14];
    const float* ob1 = (const float*)d_in[15];
    const float* ow2 = (const float*)d_in[16];
    const float* ob2 = (const float*)d_in[17];
    const float* ow3 = (const float*)d_in[18];
    const float* ob3 = (const float*)d_in[19];

    char* ws = (char*)d_ws;
    size_t off = 0;
    auto alloc = [&](size_t bytes) -> void* {
        void* p = ws + off;
        off += (bytes + 255) & ~(size_t)255;
        return p;
    };
    u16*   h0    = (u16*)  alloc((size_t)N_NODES * 64 * 2);
    u16*   h1    = (u16*)  alloc((size_t)N_NODES * 64 * 2);
    u16*   q     = (u16*)  alloc((size_t)N_NODES * 256 * 2);
    u8*    kv    = (u8*)   alloc((size_t)N_NODES * 512);
    float* skp   = (float*)alloc((size_t)N_NODES * 64 * 4);
    u16*   w16   = (u16*)  alloc((size_t)212992 * 2);
    int*   cnt   = (int*)  alloc((size_t)N_NODES * 4);   // cnt+cursor contiguous (each padded to 200192)
    int*   cursor= (int*)  alloc((size_t)N_NODES * 4);
    int*   rowst = (int*)  alloc((size_t)(N_NODES + 1) * 4);
    int*   csr   = (int*)  alloc((size_t)N_EDGES * 4);
    int*   bsum  = (int*)  alloc(512);
    int*   flag  = (int*)  alloc(256);

    u16* wq16  = w16;
    u16* wk16  = w16 + 65536;
    u16* wv16  = w16 + 131072;
    u16* wsk16 = w16 + 196608;

    const int NB = (N_NODES + 511) / 512;   // 98 scan blocks

    // zero cnt+cursor in one memset (adjacent 200192-byte padded allocations)
    hipMemsetAsync(cnt, 0, 2 * 200192, stream);
    detect_kernel<<<1, 256, 0, stream>>>(ei, flag);
    wcvt_kernel<<<208, 256, 0, stream>>>(Wq, Wk, Wv, Wsk, w16);
    hist_kernel<<<(N_EDGES + 255) / 256, 256, 0, stream>>>(ei, flag, cnt);
    scan1_kernel<<<NB, 512, 0, stream>>>(cnt, rowst, bsum);
    scan2_kernel<<<1, 128, 0, stream>>>(bsum, rowst);
    scan3_kernel<<<NB, 512, 0, stream>>>(rowst, bsum);
    scatter_kernel<<<(N_EDGES + 255) / 256, 256, 0, stream>>>(ei, flag, rowst, cursor, csr);

    encoder_kernel<<<(N_NODES + 63) / 64, 256, 0, stream>>>(x, ew1, eb1, ew2, eb2, h0);

    u16* hin = h0;
    u16* hout = h1;
    for (int l = 0; l < 4; ++l) {
        proj_kernel<<<(N_NODES + 127) / 128, 256, 0, stream>>>(hin, wq16, wk16, wv16, wsk16,
                                                               bq, bk, bv, bsk, l, q, kv, skp);
        attn_kernel<<<(N_NODES + 3) / 4, 256, 0, stream>>>(q, kv, skp, rowst, csr, hout);
        u16* tmp = hin; hin = hout; hout = tmp;
    }

    mlp_kernel<<<(N_NODES + 63) / 64, 256, 0, stream>>>(hin, ow1, ob1, ow2, ob2, ow3, ob3, (float*)d_out);
}

// Round 7
// 415.392 us; speedup vs baseline: 1.6776x; 1.0634x over previous
//
#include <hip/hip_runtime.h>
#include <hip/hip_bf16.h>

#define N_NODES 50000
#define N_EDGES 500000
constexpr int HID = 64;
constexpr int HC  = 256;   // HEADS*HID

typedef unsigned short u16;
typedef unsigned char u8;
typedef __attribute__((ext_vector_type(8))) __bf16 bf16x8;
typedef __attribute__((ext_vector_type(4))) float f32x4;
typedef __attribute__((ext_vector_type(2))) float f32x2;

__device__ __forceinline__ float b2f(u16 u) {
    union { unsigned int i; float f; } c; c.i = ((unsigned int)u) << 16; return c.f;
}
__device__ __forceinline__ u16 f2b(float f) {
    union { float f; unsigned int i; } c; c.f = f;
    unsigned int x = c.i;
    unsigned int lsb = (x >> 16) & 1u;
    x += 0x7fffu + lsb;
    return (u16)(x >> 16);
}
__device__ __forceinline__ float elu_f(float x) { return x > 0.f ? x : expm1f(x); }

// h: bf16 everywhere. q: fp8 e4m3 scale 16 (like k). skip: bf16.
// kv fp8 layout (scale 16, e4m3): group g (8B) = [k ch 4g..4g+3][v ch 4g..4g+3]

// ---------------- edge_index layout detect (int32 vs int64) ----------------
__global__ __launch_bounds__(256) void detect_kernel(const int* __restrict__ ei, int* __restrict__ flag) {
    __shared__ int s[4];
    int t = threadIdx.x;
    int nz = ei[2 * t + 1] != 0;
    unsigned long long m = __ballot(nz);
    if ((t & 63) == 0) s[t >> 6] = (m != 0ull) ? 1 : 0;
    __syncthreads();
    if (t == 0) flag[0] = s[0] | s[1] | s[2] | s[3];   // 1 => int32 layout
}

// ---------------- weight pre-conversion fp32 -> bf16 (once) ----------------
__global__ __launch_bounds__(256) void wcvt_kernel(const float* __restrict__ Wq, const float* __restrict__ Wk,
                                                   const float* __restrict__ Wv, const float* __restrict__ Wsk,
                                                   u16* __restrict__ w16) {
    int i = blockIdx.x * 256 + threadIdx.x;   // float4 index
    if (i >= 53248) return;
    const float* src; int off;
    if (i < 16384)      { src = Wq;  off = i; }
    else if (i < 32768) { src = Wk;  off = i - 16384; }
    else if (i < 49152) { src = Wv;  off = i - 32768; }
    else                { src = Wsk; off = i - 49152; }
    float4 v = ((const float4*)src)[off];
    ushort4 u; u.x = f2b(v.x); u.y = f2b(v.y); u.z = f2b(v.z); u.w = f2b(v.w);
    ((ushort4*)w16)[i] = u;
}

// ---------------- CSR build (counting sort by dst) ----------------
__global__ __launch_bounds__(256) void hist_kernel(const int* __restrict__ ei, const int* __restrict__ flag,
                                                   int* __restrict__ cnt) {
    int e = blockIdx.x * 256 + threadIdx.x;
    if (e < N_EDGES) {
        int d = flag[0] ? ei[N_EDGES + e] : ei[2 * N_EDGES + 2 * e];
        atomicAdd(&cnt[d], 1);
    }
}

__global__ __launch_bounds__(512) void scan1_kernel(const int* __restrict__ cnt,
                                                    int* __restrict__ row_start, int* __restrict__ bsum) {
    __shared__ int sc[512];
    int t = threadIdx.x;
    int i = blockIdx.x * 512 + t;
    int v = (i < N_NODES) ? cnt[i] : 0;
    sc[t] = v;
    __syncthreads();
    for (int off = 1; off < 512; off <<= 1) {
        int u = (t >= off) ? sc[t - off] : 0;
        __syncthreads();
        sc[t] += u;
        __syncthreads();
    }
    if (i < N_NODES) row_start[i] = sc[t] - v;
    if (t == 511) bsum[blockIdx.x] = sc[511];
}

__global__ __launch_bounds__(128) void scan2_kernel(int* __restrict__ bsum, int* __restrict__ row_start) {
    __shared__ int sc[128];
    const int NB = (N_NODES + 511) / 512;  // 98
    int t = threadIdx.x;
    int v = (t < NB) ? bsum[t] : 0;
    sc[t] = v;
    __syncthreads();
    for (int off = 1; off < 128; off <<= 1) {
        int u = (t >= off) ? sc[t - off] : 0;
        __syncthreads();
        sc[t] += u;
        __syncthreads();
    }
    if (t < NB) bsum[t] = sc[t] - v;
    if (t == 127) row_start[N_NODES] = sc[127];
}

__global__ __launch_bounds__(512) void scan3_kernel(int* __restrict__ row_start, const int* __restrict__ bsum) {
    int i = blockIdx.x * 512 + threadIdx.x;
    if (i < N_NODES) row_start[i] += bsum[blockIdx.x];
}

__global__ __launch_bounds__(256) void scatter_kernel(const int* __restrict__ ei, const int* __restrict__ flag,
                                const int* __restrict__ row_start, int* __restrict__ cursor,
                                int* __restrict__ csr_src) {
    int e = blockIdx.x * 256 + threadIdx.x;
    if (e < N_EDGES) {
        int isI32 = flag[0];
        int s = isI32 ? ei[e] : ei[2 * e];
        int d = isI32 ? ei[N_EDGES + e] : ei[2 * N_EDGES + 2 * e];
        int pos = row_start[d] + atomicAdd(&cursor[d], 1);
        csr_src[pos] = s;
    }
}

// ---------------- Encoder: 8->64 elu (VALU) -> 64->64 elu (MFMA), bf16 out ----------------
__global__ __launch_bounds__(256) void encoder_kernel(const float* __restrict__ x,
                               const float* __restrict__ w1, const float* __restrict__ b1,
                               const float* __restrict__ w2, const float* __restrict__ b2,
                               u16* __restrict__ h) {
    __shared__ float xs[64 * 9];
    __shared__ float w1s[64 * 9];
    __shared__ u16 t1s[64 * 72];
    __shared__ u16 w2s[64 * 72];
    __shared__ float b1s[64], b2s[64];
    int t = threadIdx.x;
    int m0 = blockIdx.x * 64;

    if (t < 128) {
        int row = t >> 1, c = (t & 1) * 4;
        float4 val = make_float4(0.f, 0.f, 0.f, 0.f);
        if (m0 + row < N_NODES) val = *(const float4*)(x + (size_t)(m0 + row) * 8 + c);
        *(float4*)&xs[row * 9 + c] = val;
    }
    if (t >= 128 && t < 256) {
        int p = t - 128;
        int row = p >> 1, c = (p & 1) * 4;
        float4 val = *(const float4*)(w1 + row * 8 + c);
        *(float4*)&w1s[row * 9 + c] = val;
    }
    #pragma unroll
    for (int r = 0; r < 4; ++r) {
        int p = t + r * 256; int row = p >> 4, kc = (p & 15) * 4;
        float4 val = *(const float4*)(w2 + row * 64 + kc);
        ushort4 u; u.x = f2b(val.x); u.y = f2b(val.y); u.z = f2b(val.z); u.w = f2b(val.w);
        *(ushort4*)&w2s[row * 72 + kc] = u;
    }
    if (t < 64) { b1s[t] = b1[t]; b2s[t] = b2[t]; }
    __syncthreads();

    {
        int j = t & 63, sub = t >> 6;
        #pragma unroll
        for (int g = 0; g < 16; ++g) {
            int node = g * 4 + sub;
            float acc = b1s[j];
            #pragma unroll
            for (int m = 0; m < 8; ++m) acc += xs[node * 9 + m] * w1s[j * 9 + m];
            t1s[node * 72 + j] = f2b(elu_f(acc));
        }
    }
    __syncthreads();

    int wave = t >> 6, lane = t & 63;
    int lrow = lane & 15, quad = lane >> 4;
    int m_off = wave * 16;
    bf16x8 a0 = *(const bf16x8*)&t1s[(m_off + lrow) * 72 + quad * 8];
    bf16x8 a1 = *(const bf16x8*)&t1s[(m_off + lrow) * 72 + 32 + quad * 8];
    #pragma unroll
    for (int nsub = 0; nsub < 4; ++nsub) {
        bf16x8 b0 = *(const bf16x8*)&w2s[(nsub * 16 + lrow) * 72 + quad * 8];
        bf16x8 b1v = *(const bf16x8*)&w2s[(nsub * 16 + lrow) * 72 + 32 + quad * 8];
        f32x4 acc = {0.f, 0.f, 0.f, 0.f};
        acc = __builtin_amdgcn_mfma_f32_16x16x32_bf16(a0, b0, acc, 0, 0, 0);
        acc = __builtin_amdgcn_mfma_f32_16x16x32_bf16(a1, b1v, acc, 0, 0, 0);
        int col = nsub * 16 + lrow;
        float bias = b2s[col];
        #pragma unroll
        for (int r = 0; r < 4; ++r) {
            int row = m0 + m_off + quad * 4 + r;
            if (row < N_NODES) h[(size_t)row * 64 + col] = f2b(elu_f(acc[r] + bias));
        }
    }
}

// ---------------- Projection v5: 128 nodes/block, double-buffered weights,
// q out = fp8 e4m3 (scale 16, like k), skip out = bf16. ----------------
__global__ __launch_bounds__(256) void proj_kernel(const u16* __restrict__ h,
    const u16* __restrict__ wq16, const u16* __restrict__ wk16,
    const u16* __restrict__ wv16, const u16* __restrict__ wsk16,
    const float* __restrict__ bq, const float* __restrict__ bk,
    const float* __restrict__ bv, const float* __restrict__ bsk,
    int layer,
    u8* __restrict__ qv, u8* __restrict__ kv, u16* __restrict__ skip)
{
    __shared__ u16 wsA[64 * 72];            // double-buffered weight tile / h stage lo
    __shared__ u16 wsB[64 * 72];            // double-buffered weight tile / h stage hi
    __shared__ __align__(16) u8 poolraw[128 * 144];  // 18432 B staging pool
    u8*  qst  = poolraw;                    // stride 80 B/node (64 fp8 + pad)
    u8*  kvst = poolraw;                    // stride 144 B/node
    u16* skst = (u16*)poolraw;              // stride 72 u16/node (144 B)

    int t = threadIdx.x;
    int m0 = blockIdx.x * 128;
    int wave = t >> 6, lane = t & 63;
    int lrow = lane & 15, quad = lane >> 4;
    int nl0 = wave * 16 + lrow;          // node set 0: 0..63
    int nl1 = 64 + nl0;                  // node set 1: 64..127

    const u16* Wq16  = wq16  + (size_t)layer * HC * HID;
    const u16* Wk16  = wk16  + (size_t)layer * HC * HID;
    const u16* Wv16  = wv16  + (size_t)layer * HC * HID;
    const u16* Wsk16 = wsk16 + (size_t)layer * HID * HID;
    const float* bqL  = bq  + layer * HC;
    const float* bkL  = bk  + layer * HC;
    const float* bvL  = bv  + layer * HC;
    const float* bskL = bsk + layer * HID;

    auto stageIssue = [&](const u16* W, int cb, uint4& r0, uint4& r1) {
        const u16* sp = W + (size_t)(cb + (t >> 3)) * 64 + (t & 7) * 8;
        r0 = *(const uint4*)sp;
        r1 = *(const uint4*)(sp + 2048);    // +32 rows
    };
    auto stageWrite = [&](u16* buf, uint4 r0, uint4 r1) {
        int row = t >> 3, kc = (t & 7) * 8;
        *(uint4*)&buf[row * 72 + kc] = r0;
        *(uint4*)&buf[(row + 32) * 72 + kc] = r1;
    };

    // ---- prologue: issue h (16KB) + Q0 weight loads, then stage ----
    uint4 hv[4];
    #pragma unroll
    for (int it = 0; it < 4; ++it) {
        int p = t + it * 256; int row = p >> 3, kc = (p & 7) * 8;
        hv[it] = make_uint4(0u, 0u, 0u, 0u);
        if (m0 + row < N_NODES) hv[it] = *(const uint4*)(h + (size_t)(m0 + row) * 64 + kc);
    }
    uint4 q0r0, q0r1;
    stageIssue(Wq16, 0, q0r0, q0r1);
    #pragma unroll
    for (int it = 0; it < 4; ++it) {
        int p = t + it * 256; int row = p >> 3, kc = (p & 7) * 8;
        if (row < 64) *(uint4*)&wsA[row * 72 + kc] = hv[it];
        else          *(uint4*)&wsB[(row - 64) * 72 + kc] = hv[it];
    }
    __syncthreads();
    bf16x8 a0 = *(const bf16x8*)&wsA[nl0 * 72 + quad * 8];
    bf16x8 a1 = *(const bf16x8*)&wsA[nl0 * 72 + 32 + quad * 8];
    bf16x8 a2 = *(const bf16x8*)&wsB[nl0 * 72 + quad * 8];
    bf16x8 a3 = *(const bf16x8*)&wsB[nl0 * 72 + 32 + quad * 8];
    __syncthreads();
    stageWrite(wsB, q0r0, q0r1);
    __syncthreads();

    auto computeQ = [&](int ct, const u16* BUF) {
        #pragma unroll
        for (int nsub = 0; nsub < 4; ++nsub) {
            bf16x8 w0 = *(const bf16x8*)&BUF[(nsub * 16 + lrow) * 72 + quad * 8];
            bf16x8 w1 = *(const bf16x8*)&BUF[(nsub * 16 + lrow) * 72 + 32 + quad * 8];
            float4 b4 = *(const float4*)(bqL + ct * 64 + nsub * 16 + quad * 4);
            int c4 = nsub * 16 + quad * 4;
            f32x4 acc = {0.f, 0.f, 0.f, 0.f};
            acc = __builtin_amdgcn_mfma_f32_16x16x32_bf16(w0, a0, acc, 0, 0, 0);
            acc = __builtin_amdgcn_mfma_f32_16x16x32_bf16(w1, a1, acc, 0, 0, 0);
            {
                float f0 = (acc[0] + b4.x) * 16.f, f1 = (acc[1] + b4.y) * 16.f;
                float f2v = (acc[2] + b4.z) * 16.f, f3v = (acc[3] + b4.w) * 16.f;
                int pk = __builtin_amdgcn_cvt_pk_fp8_f32(f0, f1, 0, false);
                pk = __builtin_amdgcn_cvt_pk_fp8_f32(f2v, f3v, pk, true);
                *(unsigned int*)&qst[nl0 * 80 + c4] = (unsigned int)pk;
            }
            f32x4 acc2 = {0.f, 0.f, 0.f, 0.f};
            acc2 = __builtin_amdgcn_mfma_f32_16x16x32_bf16(w0, a2, acc2, 0, 0, 0);
            acc2 = __builtin_amdgcn_mfma_f32_16x16x32_bf16(w1, a3, acc2, 0, 0, 0);
            {
                float f0 = (acc2[0] + b4.x) * 16.f, f1 = (acc2[1] + b4.y) * 16.f;
                float f2v = (acc2[2] + b4.z) * 16.f, f3v = (acc2[3] + b4.w) * 16.f;
                int pk = __builtin_amdgcn_cvt_pk_fp8_f32(f0, f1, 0, false);
                pk = __builtin_amdgcn_cvt_pk_fp8_f32(f2v, f3v, pk, true);
                *(unsigned int*)&qst[nl1 * 80 + c4] = (unsigned int)pk;
            }
        }
    };
    auto computeKV = [&](int ct, const u16* BUF, const float* bias, int voff) {
        #pragma unroll
        for (int nsub = 0; nsub < 4; ++nsub) {
            bf16x8 w0 = *(const bf16x8*)&BUF[(nsub * 16 + lrow) * 72 + quad * 8];
            bf16x8 w1 = *(const bf16x8*)&BUF[(nsub * 16 + lrow) * 72 + 32 + quad * 8];
            float4 b4 = *(const float4*)(bias + ct * 64 + nsub * 16 + quad * 4);
            int g = nsub * 4 + quad;
            f32x4 acc = {0.f, 0.f, 0.f, 0.f};
            acc = __builtin_amdgcn_mfma_f32_16x16x32_bf16(w0, a0, acc, 0, 0, 0);
            acc = __builtin_amdgcn_mfma_f32_16x16x32_bf16(w1, a1, acc, 0, 0, 0);
            {
                float f0 = (acc[0] + b4.x) * 16.f, f1 = (acc[1] + b4.y) * 16.f;
                float f2v = (acc[2] + b4.z) * 16.f, f3v = (acc[3] + b4.w) * 16.f;
                int pk = __builtin_amdgcn_cvt_pk_fp8_f32(f0, f1, 0, false);
                pk = __builtin_amdgcn_cvt_pk_fp8_f32(f2v, f3v, pk, true);
                *(unsigned int*)&kvst[nl0 * 144 + g * 8 + voff] = (unsigned int)pk;
            }
            f32x4 acc2 = {0.f, 0.f, 0.f, 0.f};
            acc2 = __builtin_amdgcn_mfma_f32_16x16x32_bf16(w0, a2, acc2, 0, 0, 0);
            acc2 = __builtin_amdgcn_mfma_f32_16x16x32_bf16(w1, a3, acc2, 0, 0, 0);
            {
                float f0 = (acc2[0] + b4.x) * 16.f, f1 = (acc2[1] + b4.y) * 16.f;
                float f2v = (acc2[2] + b4.z) * 16.f, f3v = (acc2[3] + b4.w) * 16.f;
                int pk = __builtin_amdgcn_cvt_pk_fp8_f32(f0, f1, 0, false);
                pk = __builtin_amdgcn_cvt_pk_fp8_f32(f2v, f3v, pk, true);
                *(unsigned int*)&kvst[nl1 * 144 + g * 8 + voff] = (unsigned int)pk;
            }
        }
    };
    auto computeSK = [&](const u16* BUF) {
        #pragma unroll
        for (int nsub = 0; nsub < 4; ++nsub) {
            bf16x8 w0 = *(const bf16x8*)&BUF[(nsub * 16 + lrow) * 72 + quad * 8];
            bf16x8 w1 = *(const bf16x8*)&BUF[(nsub * 16 + lrow) * 72 + 32 + quad * 8];
            float4 b4 = *(const float4*)(bskL + nsub * 16 + quad * 4);
            int c4 = nsub * 16 + quad * 4;
            f32x4 acc = {0.f, 0.f, 0.f, 0.f};
            acc = __builtin_amdgcn_mfma_f32_16x16x32_bf16(w0, a0, acc, 0, 0, 0);
            acc = __builtin_amdgcn_mfma_f32_16x16x32_bf16(w1, a1, acc, 0, 0, 0);
            ushort4 s4;
            s4.x = f2b(acc[0] + b4.x); s4.y = f2b(acc[1] + b4.y);
            s4.z = f2b(acc[2] + b4.z); s4.w = f2b(acc[3] + b4.w);
            *(ushort4*)&skst[nl0 * 72 + c4] = s4;
            f32x4 acc2 = {0.f, 0.f, 0.f, 0.f};
            acc2 = __builtin_amdgcn_mfma_f32_16x16x32_bf16(w0, a2, acc2, 0, 0, 0);
            acc2 = __builtin_amdgcn_mfma_f32_16x16x32_bf16(w1, a3, acc2, 0, 0, 0);
            ushort4 s5;
            s5.x = f2b(acc2[0] + b4.x); s5.y = f2b(acc2[1] + b4.y);
            s5.z = f2b(acc2[2] + b4.z); s5.w = f2b(acc2[3] + b4.w);
            *(ushort4*)&skst[nl1 * 72 + c4] = s5;
        }
    };
    auto flushQ = [&](int ct) {
        #pragma unroll
        for (int it = 0; it < 2; ++it) {
            int p = t + it * 256; int row = p >> 2, ch = p & 3;
            int grow = m0 + row;
            if (grow < N_NODES)
                *(uint4*)(qv + (size_t)grow * 256 + ct * 64 + ch * 16) = *(const uint4*)&qst[row * 80 + ch * 16];
        }
    };
    auto flushKV = [&](int ct) {
        #pragma unroll
        for (int it = 0; it < 4; ++it) {
            int p = t + it * 256; int row = p >> 3, ch = p & 7;
            int grow = m0 + row;
            if (grow < N_NODES)
                *(uint4*)(kv + (size_t)grow * 512 + ct * 128 + ch * 16) = *(const uint4*)&kvst[row * 144 + ch * 16];
        }
    };

    uint4 r0, r1;
    // tiles: Q0(B) Q1(A) Q2(B) Q3(A) K0(B) V0(A) K1(B) V1(A) K2(B) V2(A) K3(B) V3(A) SK(B)
    stageIssue(Wq16, 64, r0, r1);  computeQ(0, wsB);          __syncthreads(); flushQ(0);  stageWrite(wsA, r0, r1); __syncthreads();
    stageIssue(Wq16, 128, r0, r1); computeQ(1, wsA);          __syncthreads(); flushQ(1);  stageWrite(wsB, r0, r1); __syncthreads();
    stageIssue(Wq16, 192, r0, r1); computeQ(2, wsB);          __syncthreads(); flushQ(2);  stageWrite(wsA, r0, r1); __syncthreads();
    stageIssue(Wk16, 0, r0, r1);   computeQ(3, wsA);          __syncthreads(); flushQ(3);  stageWrite(wsB, r0, r1); __syncthreads();
    stageIssue(Wv16, 0, r0, r1);   computeKV(0, wsB, bkL, 0); __syncthreads();             stageWrite(wsA, r0, r1); __syncthreads();
    stageIssue(Wk16, 64, r0, r1);  computeKV(0, wsA, bvL, 4); __syncthreads(); flushKV(0); stageWrite(wsB, r0, r1); __syncthreads();
    stageIssue(Wv16, 64, r0, r1);  computeKV(1, wsB, bkL, 0); __syncthreads();             stageWrite(wsA, r0, r1); __syncthreads();
    stageIssue(Wk16, 128, r0, r1); computeKV(1, wsA, bvL, 4); __syncthreads(); flushKV(1); stageWrite(wsB, r0, r1); __syncthreads();
    stageIssue(Wv16, 128, r0, r1); computeKV(2, wsB, bkL, 0); __syncthreads();             stageWrite(wsA, r0, r1); __syncthreads();
    stageIssue(Wk16, 192, r0, r1); computeKV(2, wsA, bvL, 4); __syncthreads(); flushKV(2); stageWrite(wsB, r0, r1); __syncthreads();
    stageIssue(Wv16, 192, r0, r1); computeKV(3, wsB, bkL, 0); __syncthreads();             stageWrite(wsA, r0, r1); __syncthreads();
    stageIssue(Wsk16, 0, r0, r1);  computeKV(3, wsA, bvL, 4); __syncthreads(); flushKV(3); stageWrite(wsB, r0, r1); __syncthreads();

    // ---- last phase: skip tile (bf16 out) ----
    computeSK(wsB);
    __syncthreads();
    #pragma unroll
    for (int it = 0; it < 4; ++it) {
        int p = t + it * 256; int row = p >> 3, ch = p & 7;
        int grow = m0 + row;
        if (grow < N_NODES)
            *(uint4*)(skip + (size_t)grow * 64 + ch * 8) = *(const uint4*)&skst[row * 72 + ch * 8];
    }
}

// ---------------- Attention v6: fp8 q (scale folded into SC), bf16 skip,
// DPP 16-lane butterfly, LDS-broadcast CSR. ----------------
#define DPP_ADD(x, ctrl) ((x) + __builtin_bit_cast(float, \
    __builtin_amdgcn_update_dpp(0, __builtin_bit_cast(int, (x)), (ctrl), 0xf, 0xf, true)))

#define ATTN_QUAD(S0q, S1q, S2q, S3q, V1, V2, V3) do { \
    uint2 c0 = *(const uint2*)(kvl + (size_t)(unsigned)(S0q) * 512); \
    uint2 c1 = *(const uint2*)(kvl + (size_t)(unsigned)(S1q) * 512); \
    uint2 c2 = *(const uint2*)(kvl + (size_t)(unsigned)(S2q) * 512); \
    uint2 c3 = *(const uint2*)(kvl + (size_t)(unsigned)(S3q) * 512); \
    f32x2 k0a = __builtin_amdgcn_cvt_pk_f32_fp8(c0.x, false), k0b = __builtin_amdgcn_cvt_pk_f32_fp8(c0.x, true); \
    f32x2 k1a = __builtin_amdgcn_cvt_pk_f32_fp8(c1.x, false), k1b = __builtin_amdgcn_cvt_pk_f32_fp8(c1.x, true); \
    f32x2 k2a = __builtin_amdgcn_cvt_pk_f32_fp8(c2.x, false), k2b = __builtin_amdgcn_cvt_pk_f32_fp8(c2.x, true); \
    f32x2 k3a = __builtin_amdgcn_cvt_pk_f32_fp8(c3.x, false), k3b = __builtin_amdgcn_cvt_pk_f32_fp8(c3.x, true); \
    f32x2 pd0 = qlo * k0a + qhi * k0b; \
    f32x2 pd1 = qlo * k1a + qhi * k1b; \
    f32x2 pd2 = qlo * k2a + qhi * k2b; \
    f32x2 pd3 = qlo * k3a + qhi * k3b; \
    float p0 = pd0.x + pd0.y, p1 = pd1.x + pd1.y, p2 = pd2.x + pd2.y, p3 = pd3.x + pd3.y; \
    p0 = DPP_ADD(p0, 0xB1);  p1 = DPP_ADD(p1, 0xB1);  p2 = DPP_ADD(p2, 0xB1);  p3 = DPP_ADD(p3, 0xB1);  \
    p0 = DPP_ADD(p0, 0x4E);  p1 = DPP_ADD(p1, 0x4E);  p2 = DPP_ADD(p2, 0x4E);  p3 = DPP_ADD(p3, 0x4E);  \
    p0 = DPP_ADD(p0, 0x141); p1 = DPP_ADD(p1, 0x141); p2 = DPP_ADD(p2, 0x141); p3 = DPP_ADD(p3, 0x141); \
    p0 = DPP_ADD(p0, 0x140); p1 = DPP_ADD(p1, 0x140); p2 = DPP_ADD(p2, 0x140); p3 = DPP_ADD(p3, 0x140); \
    float w0 = __expf(p0 * SC); \
    float w1 = (V1) ? __expf(p1 * SC) : 0.f; \
    float w2 = (V2) ? __expf(p2 * SC) : 0.f; \
    float w3 = (V3) ? __expf(p3 * SC) : 0.f; \
    l += (w0 + w1) + (w2 + w3); \
    f32x2 v0a = __builtin_amdgcn_cvt_pk_f32_fp8(c0.y, false), v0b = __builtin_amdgcn_cvt_pk_f32_fp8(c0.y, true); \
    f32x2 v1a = __builtin_amdgcn_cvt_pk_f32_fp8(c1.y, false), v1b = __builtin_amdgcn_cvt_pk_f32_fp8(c1.y, true); \
    f32x2 v2a = __builtin_amdgcn_cvt_pk_f32_fp8(c2.y, false), v2b = __builtin_amdgcn_cvt_pk_f32_fp8(c2.y, true); \
    f32x2 v3a = __builtin_amdgcn_cvt_pk_f32_fp8(c3.y, false), v3b = __builtin_amdgcn_cvt_pk_f32_fp8(c3.y, true); \
    accA += v0a * w0; accA += v1a * w1; accA += v2a * w2; accA += v3a * w3; \
    accB += v0b * w0; accB += v1b * w1; accB += v2b * w2; accB += v3b * w3; \
} while (0)

__global__ __launch_bounds__(256) void attn_kernel(
    const u8* __restrict__ q, const u8* __restrict__ kv,
    const u16* __restrict__ skip,
    const int* __restrict__ row_start, const int* __restrict__ csr_src,
    u16* __restrict__ hout)
{
    __shared__ int s_lds[4][64];     // per-wave private row: no barrier needed
    int wave = threadIdx.x >> 6;
    int lane = threadIdx.x & 63;
    int n = blockIdx.x * 4 + wave;
    if (n >= N_NODES) return;
    unsigned qw = ((const unsigned*)(q + (size_t)n * 256))[lane];
    f32x2 qlo = __builtin_amdgcn_cvt_pk_f32_fp8(qw, false);
    f32x2 qhi = __builtin_amdgcn_cvt_pk_f32_fp8(qw, true);
    ushort4 sk4 = make_ushort4(0, 0, 0, 0);
    if ((lane >> 4) == 0) sk4 = ((const ushort4*)(skip + (size_t)n * 64))[lane];
    const u8* kvl = kv + lane * 8;
    const float SC = 4.8828125e-4f;   // 1/(8*16*16): sqrt(d), k-scale, q-scale
    float l = 0.f;
    f32x2 accA = {0.f, 0.f};
    f32x2 accB = {0.f, 0.f};
    int e0 = row_start[n];
    int deg = row_start[n + 1] - e0;

    for (int base = 0; base < deg; base += 64) {
        int rem = deg - base;
        int m = rem < 64 ? rem : 64;
        int li = lane < m ? lane : m - 1;           // clamp: stay inside this row's edges
        s_lds[wave][lane] = csr_src[e0 + base + li]; // one coalesced load per 64 edges
        int i = 0;
        for (; i + 4 <= m; i += 4) {
            int4 sq = *(const int4*)&s_lds[wave][i];  // uniform addr -> LDS broadcast
            ATTN_QUAD(sq.x, sq.y, sq.z, sq.w, 1, 1, 1);
        }
        if (i < m) {                                  // tail: 1..3 edges, masked quad
            int4 sq = *(const int4*)&s_lds[wave][i];  // i%4==0, i<=60: aligned, in-bounds
            int rem2 = m - i;
            int sB = rem2 > 1 ? sq.y : sq.x;
            int sC = rem2 > 2 ? sq.z : sq.x;
            ATTN_QUAD(sq.x, sB, sC, sq.x, rem2 > 1, rem2 > 2, 0);
        }
    }

    float inv = l > 0.f ? 1.f / l : 0.f;
    float a0 = accA.x * inv, a1 = accA.y * inv;
    float a2 = accB.x * inv, a3 = accB.y * inv;
    a0 += __shfl_xor(a0, 16); a0 += __shfl_xor(a0, 32);
    a1 += __shfl_xor(a1, 16); a1 += __shfl_xor(a1, 32);
    a2 += __shfl_xor(a2, 16); a2 += __shfl_xor(a2, 32);
    a3 += __shfl_xor(a3, 16); a3 += __shfl_xor(a3, 32);
    if ((lane >> 4) == 0) {
        const float OS = 0.015625f;  // 0.25 (head mean) * 1/16 (v scale)
        ushort4 o;
        o.x = f2b(elu_f(OS * a0 + b2f(sk4.x)));
        o.y = f2b(elu_f(OS * a1 + b2f(sk4.y)));
        o.z = f2b(elu_f(OS * a2 + b2f(sk4.z)));
        o.w = f2b(elu_f(OS * a3 + b2f(sk4.w)));
        ((ushort4*)(hout + (size_t)n * 64))[lane] = o;
    }
}

// ---------------- Output MLP: 64->64 elu (MFMA) ->32 elu (MFMA) ->8 (VALU),
// bf16 h input ----------------
__global__ __launch_bounds__(256) void mlp_kernel(const u16* __restrict__ h,
    const float* __restrict__ w1, const float* __restrict__ b1,
    const float* __restrict__ w2, const float* __restrict__ b2,
    const float* __restrict__ w3, const float* __restrict__ b3,
    float* __restrict__ out)
{
    __shared__ u16 hs[64 * 72];
    __shared__ u16 w1s[64 * 72];
    __shared__ u16 t1s[64 * 72];
    __shared__ u16 w2s[32 * 72];
    __shared__ float t2s[64 * 33];
    __shared__ float w3s[8 * 33];
    __shared__ float b1s[64], b2s[32], b3s[8];
    int t = threadIdx.x;
    int m0 = blockIdx.x * 64;

    #pragma unroll
    for (int it = 0; it < 2; ++it) {
        int p = t + it * 256; int row = p >> 3, kc = (p & 7) * 8;
        uint4 val = make_uint4(0u, 0u, 0u, 0u);
        if (m0 + row < N_NODES) val = *(const uint4*)(h + (size_t)(m0 + row) * 64 + kc);
        *(uint4*)&hs[row * 72 + kc] = val;
    }
    #pragma unroll
    for (int r = 0; r < 4; ++r) {
        int p = t + r * 256; int row = p >> 4, kc = (p & 15) * 4;
        float4 val = *(const float4*)(w1 + row * 64 + kc);
        ushort4 u; u.x = f2b(val.x); u.y = f2b(val.y); u.z = f2b(val.z); u.w = f2b(val.w);
        *(ushort4*)&w1s[row * 72 + kc] = u;
    }
    #pragma unroll
    for (int r = 0; r < 2; ++r) {
        int p = t + r * 256; int row = p >> 4, kc = (p & 15) * 4;
        float4 val = *(const float4*)(w2 + row * 64 + kc);
        ushort4 u; u.x = f2b(val.x); u.y = f2b(val.y); u.z = f2b(val.z); u.w = f2b(val.w);
        *(ushort4*)&w2s[row * 72 + kc] = u;
    }
    if (t < 8 * 32) { int r = t >> 5, c = t & 31; w3s[r * 33 + c] = w3[t]; }
    if (t < 64) b1s[t] = b1[t];
    if (t >= 64 && t < 96) b2s[t - 64] = b2[t - 64];
    if (t >= 96 && t < 104) b3s[t - 96] = b3[t - 96];
    __syncthreads();

    int wave = t >> 6, lane = t & 63;
    int lrow = lane & 15, quad = lane >> 4;
    int m_off = wave * 16;

    {
        bf16x8 a0 = *(const bf16x8*)&hs[(m_off + lrow) * 72 + quad * 8];
        bf16x8 a1 = *(const bf16x8*)&hs[(m_off + lrow) * 72 + 32 + quad * 8];
        #pragma unroll
        for (int nsub = 0; nsub < 4; ++nsub) {
            bf16x8 b0 = *(const bf16x8*)&w1s[(nsub * 16 + lrow) * 72 + quad * 8];
            bf16x8 b1v = *(const bf16x8*)&w1s[(nsub * 16 + lrow) * 72 + 32 + quad * 8];
            f32x4 acc = {0.f, 0.f, 0.f, 0.f};
            acc = __builtin_amdgcn_mfma_f32_16x16x32_bf16(a0, b0, acc, 0, 0, 0);
            acc = __builtin_amdgcn_mfma_f32_16x16x32_bf16(a1, b1v, acc, 0, 0, 0);
            int col = nsub * 16 + lrow;
            float bias = b1s[col];
            #pragma unroll
            for (int r = 0; r < 4; ++r) {
                int row = m_off + quad * 4 + r;
                t1s[row * 72 + col] = f2b(elu_f(acc[r] + bias));
            }
        }
    }
    __syncthreads();

    {
        bf16x8 a0 = *(const bf16x8*)&t1s[(m_off + lrow) * 72 + quad * 8];
        bf16x8 a1 = *(const bf16x8*)&t1s[(m_off + lrow) * 72 + 32 + quad * 8];
        #pragma unroll
        for (int nsub = 0; nsub < 2; ++nsub) {
            bf16x8 b0 = *(const bf16x8*)&w2s[(nsub * 16 + lrow) * 72 + quad * 8];
            bf16x8 b1v = *(const bf16x8*)&w2s[(nsub * 16 + lrow) * 72 + 32 + quad * 8];
            f32x4 acc = {0.f, 0.f, 0.f, 0.f};
            acc = __builtin_amdgcn_mfma_f32_16x16x32_bf16(a0, b0, acc, 0, 0, 0);
            acc = __builtin_amdgcn_mfma_f32_16x16x32_bf16(a1, b1v, acc, 0, 0, 0);
            int col = nsub * 16 + lrow;
            float bias = b2s[col];
            #pragma unroll
            for (int r = 0; r < 4; ++r) {
                int row = m_off + quad * 4 + r;
                t2s[row * 33 + col] = elu_f(acc[r] + bias);
            }
        }
    }
    __syncthreads();

    #pragma unroll
    for (int r = 0; r < 2; ++r) {
        int idx = t + r * 256;
        int node = idx >> 3, j = idx & 7;
        int row = m0 + node;
        if (row < N_NODES) {
            float acc = b3s[j];
            #pragma unroll
            for (int kk = 0; kk < 32; ++kk) acc += t2s[node * 33 + kk] * w3s[j * 33 + kk];
            out[(size_t)row * 8 + j] = acc;
        }
    }
}

extern "C" void kernel_launch(void* const* d_in, const int* in_sizes, int n_in,
                              void* d_out, int out_size, void* d_ws, size_t ws_size,
                              hipStream_t stream) {
    (void)in_sizes; (void)n_in; (void)out_size; (void)ws_size;
    const float* x   = (const float*)d_in[0];
    const int* ei    = (const int*)d_in[1];
    const float* ew1 = (const float*)d_in[2];
    const float* eb1 = (const float*)d_in[3];
    const float* ew2 = (const float*)d_in[4];
    const float* eb2 = (const float*)d_in[5];
    const float* Wq  = (const float*)d_in[6];
    const float* bq  = (const float*)d_in[7];
    const float* Wk  = (const float*)d_in[8];
    const float* bk  = (const float*)d_in[9];
    const float* Wv  = (const float*)d_in[10];
    const float* bv  = (const float*)d_in[11];
    const float* Wsk = (const float*)d_in[12];
    const float* bsk = (const float*)d_in[13];
    const float* ow1 = (const float*)d_in[14];
    const float* ob1 = (const float*)d_in[15];
    const float* ow2 = (const float*)d_in[16];
    const float* ob2 = (const float*)d_in[17];
    const float* ow3 = (const float*)d_in[18];
    const float* ob3 = (const float*)d_in[19];

    char* ws = (char*)d_ws;
    size_t off = 0;
    auto alloc = [&](size_t bytes) -> void* {
        void* p = ws + off;
        off += (bytes + 255) & ~(size_t)255;
        return p;
    };
    u16*   h0    = (u16*)  alloc((size_t)N_NODES * 64 * 2);
    u16*   h1    = (u16*)  alloc((size_t)N_NODES * 64 * 2);
    u8*    q     = (u8*)   alloc((size_t)N_NODES * 256);
    u8*    kv    = (u8*)   alloc((size_t)N_NODES * 512);
    u16*   skp   = (u16*)  alloc((size_t)N_NODES * 64 * 2);
    u16*   w16   = (u16*)  alloc((size_t)212992 * 2);
    int*   cnt   = (int*)  alloc((size_t)N_NODES * 4);   // cnt+cursor contiguous (each padded to 200192)
    int*   cursor= (int*)  alloc((size_t)N_NODES * 4);
    int*   rowst = (int*)  alloc((size_t)(N_NODES + 1) * 4);
    int*   csr   = (int*)  alloc((size_t)N_EDGES * 4);
    int*   bsum  = (int*)  alloc(512);
    int*   flag  = (int*)  alloc(256);

    u16* wq16  = w16;
    u16* wk16  = w16 + 65536;
    u16* wv16  = w16 + 131072;
    u16* wsk16 = w16 + 196608;

    const int NB = (N_NODES + 511) / 512;   // 98 scan blocks

    // zero cnt+cursor in one memset (adjacent 200192-byte padded allocations)
    hipMemsetAsync(cnt, 0, 2 * 200192, stream);
    detect_kernel<<<1, 256, 0, stream>>>(ei, flag);
    wcvt_kernel<<<208, 256, 0, stream>>>(Wq, Wk, Wv, Wsk, w16);
    hist_kernel<<<(N_EDGES + 255) / 256, 256, 0, stream>>>(ei, flag, cnt);
    scan1_kernel<<<NB, 512, 0, stream>>>(cnt, rowst, bsum);
    scan2_kernel<<<1, 128, 0, stream>>>(bsum, rowst);
    scan3_kernel<<<NB, 512, 0, stream>>>(rowst, bsum);
    scatter_kernel<<<(N_EDGES + 255) / 256, 256, 0, stream>>>(ei, flag, rowst, cursor, csr);

    encoder_kernel<<<(N_NODES + 63) / 64, 256, 0, stream>>>(x, ew1, eb1, ew2, eb2, h0);

    u16* hin = h0;
    u16* hout = h1;
    for (int l = 0; l < 4; ++l) {
        proj_kernel<<<(N_NODES + 127) / 128, 256, 0, stream>>>(hin, wq16, wk16, wv16, wsk16,
                                                               bq, bk, bv, bsk, l, q, kv, skp);
        attn_kernel<<<(N_NODES + 3) / 4, 256, 0, stream>>>(q, kv, skp, rowst, csr, hout);
        u16* tmp = hin; hin = hout; hout = tmp;
    }

    mlp_kernel<<<(N_NODES + 63) / 64, 256, 0, stream>>>(hin, ow1, ob1, ow2, ob2, ow3, ob3, (float*)d_out);
}